// Round 16
// baseline (1547.772 us; speedup 1.0000x reference)
//
#include <hip/hip_runtime.h>

#define F 64
#define TPB 256
#define SCAN_B 64
#define BN_EPS 1e-5f
#define CHUNK 4

typedef unsigned short u16;

__device__ __forceinline__ float lane_bcast(float v, int l) {
    return __int_as_float(__builtin_amdgcn_readlane(__float_as_int(v), l));
}
__device__ __forceinline__ int lane_bcast_i(int v, int l) {
    return __builtin_amdgcn_readlane(v, l);
}
__device__ __forceinline__ float bf2f(u16 u) {
    return __uint_as_float(((unsigned int)u) << 16);
}
__device__ __forceinline__ u16 f2bf(float f) {
    unsigned int u = __float_as_uint(f);
    unsigned int r = (u + 0x7fffu + ((u >> 16) & 1u)) >> 16;   // RNE
    return (u16)r;
}

// ---- CSR build ----------------------------------------------------------

__global__ __launch_bounds__(TPB) void k_hist(const int* __restrict__ dst,
                                              int* __restrict__ deg, int E) {
    int e = blockIdx.x * blockDim.x + threadIdx.x;
    if (e < E) atomicAdd(&deg[dst[e]], 1);
}

__global__ __launch_bounds__(TPB) void k_scan_part(const int* __restrict__ deg,
                                                   int* __restrict__ part, int N) {
    __shared__ int red[TPB];
    int chunk = (N + SCAN_B - 1) / SCAN_B;
    int lo = blockIdx.x * chunk, hi = min(lo + chunk, N);
    int t = threadIdx.x;
    int s = 0;
    for (int i = lo + t; i < hi; i += TPB) s += deg[i];
    red[t] = s; __syncthreads();
    for (int d = TPB / 2; d > 0; d >>= 1) {
        if (t < d) red[t] += red[t + d];
        __syncthreads();
    }
    if (t == 0) part[blockIdx.x] = red[0];
}

__global__ __launch_bounds__(TPB) void k_scan_apply(const int* __restrict__ deg,
                                                    const int* __restrict__ part,
                                                    int* __restrict__ offs,
                                                    int* __restrict__ cursor, int N) {
    __shared__ int ts[TPB];
    __shared__ int pb_s;
    int t = threadIdx.x;
    ts[t] = (t < blockIdx.x) ? part[t] : 0;
    __syncthreads();
    for (int d = TPB / 2; d > 0; d >>= 1) {
        if (t < d) ts[t] += ts[t + d];
        __syncthreads();
    }
    if (t == 0) pb_s = ts[0];
    __syncthreads();
    int pbase = pb_s;
    __syncthreads();
    int chunk = (N + SCAN_B - 1) / SCAN_B;
    int sub = (chunk + TPB - 1) / TPB;
    int lo = blockIdx.x * chunk;
    int blockhi = min(lo + chunk, N);
    int mylo = min(lo + t * sub, blockhi);
    int myhi = min(mylo + sub, blockhi);
    int s = 0;
    for (int i = mylo; i < myhi; ++i) s += deg[i];
    ts[t] = s; __syncthreads();
    for (int d = 1; d < TPB; d <<= 1) {
        int a = (t >= d) ? ts[t - d] : 0;
        __syncthreads();
        ts[t] += a;
        __syncthreads();
    }
    int run = pbase + ts[t] - s;
    for (int i = mylo; i < myhi; ++i) {
        offs[i] = run; cursor[i] = run; run += deg[i];
    }
    if (blockIdx.x == SCAN_B - 1 && t == TPB - 1) offs[N] = pbase + ts[TPB - 1];
}

__global__ __launch_bounds__(TPB) void k_fill(const int* __restrict__ src,
                                              const int* __restrict__ dst,
                                              int* __restrict__ cursor,
                                              int* __restrict__ csr_src, int E) {
    int e = blockIdx.x * blockDim.x + threadIdx.x;
    if (e >= E) return;
    int pos = atomicAdd(&cursor[dst[e]], 1);
    csr_src[pos] = src[e];
}

// ---- prep: x16 = bf16(x); Yf = x @ Wj + bias (fused, reads x once) ------
__global__ __launch_bounds__(TPB, 4)
void k_prep(const float* __restrict__ x, u16* __restrict__ x16,
            const float* __restrict__ Wj, const float* __restrict__ bias,
            float* __restrict__ Yf, int N, int rowsPerWave) {
    int t = threadIdx.x;
    int lane = t & 63, w = t >> 6;
    float wcol[F];
#pragma unroll
    for (int f = 0; f < F; ++f) wcol[f] = Wj[f * F + lane];
    float bj = bias[lane];
    int row0 = (blockIdx.x * 4 + w) * rowsPerWave;
    for (int r = 0; r < rowsPerWave; ++r) {
        int row = row0 + r;
        if (row >= N) break;
        float v = x[(size_t)row * F + lane];
        x16[(size_t)row * F + lane] = f2bf(v);
        float acc = bj;
#pragma unroll
        for (int f = 0; f < F; ++f) acc += lane_bcast(v, f) * wcol[f];
        Yf[(size_t)row * F + lane] = acc;
    }
}

// ---- fused gather + GEMM1 + BN stats (persistent + dynamic stealing) ----
// R12/R15 node-loop structure (LDS W, 16-deep gather, offs batching), but
// waves pull 4-node chunks from a global counter -> no static-assignment tail.
__global__ __launch_bounds__(TPB, 8)
void k_gather_gemm(const u16* __restrict__ h, const int* __restrict__ offs,
                   const int* __restrict__ csr,
                   const float* __restrict__ W, const float* __restrict__ bias,
                   float* __restrict__ Y, float* __restrict__ stats,
                   int* __restrict__ ctr, int N) {
    __shared__ float Wl[F * F];
    int t = threadIdx.x;
    int lane = t & 63, w = t >> 6;
    for (int i = t; i < F * F; i += TPB) Wl[i] = W[i];
    __syncthreads();
    float bj = bias[lane];
    float s1 = 0.f, s2 = 0.f;
    for (;;) {
        int c0 = 0;
        if (lane == 0) c0 = atomicAdd(ctr, CHUNK);
        int node0 = lane_bcast_i(c0, 0);
        if (node0 >= N) break;
        // offs[node0 .. node0+CHUNK] via lanes (clamped)
        int off_l = 0;
        if (lane <= CHUNK) off_l = offs[min(node0 + lane, N)];
        // prefetch node 0's first batch
        int start_n = lane_bcast_i(off_l, 0);
        int end_n   = lane_bcast_i(off_l, 1);
        int cnt_n   = min(end_n - start_n, 64);
        int idx_n   = (lane < cnt_n) ? csr[start_n + lane] : 0;
        for (int r = 0; r < CHUNK; ++r) {
            int node = node0 + r;
            if (node >= N) break;
            int start = start_n, end = end_n, cnt = cnt_n, idx = idx_n;
            if (r + 1 < CHUNK) {
                start_n = lane_bcast_i(off_l, r + 1);
                end_n   = lane_bcast_i(off_l, r + 2);
                cnt_n   = min(end_n - start_n, 64);
                idx_n   = (lane < cnt_n) ? csr[start_n + lane] : 0;
            }
            float agg = bf2f(h[(size_t)node * F + lane]);   // GIN self (eps=0)
            {
                int k = 0;
                for (; k + 16 <= cnt; k += 16) {
                    float vv[16];
#pragma unroll
                    for (int u = 0; u < 16; ++u)
                        vv[u] = bf2f(h[(size_t)lane_bcast_i(idx, k + u) * F + lane]);
                    float sA = 0.f, sB = 0.f, sC = 0.f, sD = 0.f;
#pragma unroll
                    for (int u = 0; u < 4; ++u) {
                        sA += vv[u]; sB += vv[4 + u]; sC += vv[8 + u]; sD += vv[12 + u];
                    }
                    agg += (sA + sB) + (sC + sD);
                }
                for (; k + 4 <= cnt; k += 4) {
                    float v0 = bf2f(h[(size_t)lane_bcast_i(idx, k)     * F + lane]);
                    float v1 = bf2f(h[(size_t)lane_bcast_i(idx, k + 1) * F + lane]);
                    float v2 = bf2f(h[(size_t)lane_bcast_i(idx, k + 2) * F + lane]);
                    float v3 = bf2f(h[(size_t)lane_bcast_i(idx, k + 3) * F + lane]);
                    agg += (v0 + v1) + (v2 + v3);
                }
                for (; k < cnt; ++k)
                    agg += bf2f(h[(size_t)lane_bcast_i(idx, k) * F + lane]);
            }
            for (int base = start + 64; base < end; base += 64) {
                int c2 = end - base; if (c2 > 64) c2 = 64;
                int idx2 = (lane < c2) ? csr[base + lane] : 0;
                int k = 0;
                for (; k + 4 <= c2; k += 4) {
                    float v0 = bf2f(h[(size_t)lane_bcast_i(idx2, k)     * F + lane]);
                    float v1 = bf2f(h[(size_t)lane_bcast_i(idx2, k + 1) * F + lane]);
                    float v2 = bf2f(h[(size_t)lane_bcast_i(idx2, k + 2) * F + lane]);
                    float v3 = bf2f(h[(size_t)lane_bcast_i(idx2, k + 3) * F + lane]);
                    agg += (v0 + v1) + (v2 + v3);
                }
                for (; k < c2; ++k)
                    agg += bf2f(h[(size_t)lane_bcast_i(idx2, k) * F + lane]);
            }
            float acc = bj;
#pragma unroll
            for (int f = 0; f < F; ++f) acc += lane_bcast(agg, f) * Wl[f * F + lane];
            Y[(size_t)node * F + lane] = acc;
            s1 += acc;
            s2 += acc * acc;
        }
    }
    __shared__ float red[TPB];
    red[t] = s1; __syncthreads();
    if (w == 0) atomicAdd(&stats[lane], red[lane] + red[64 + lane] + red[128 + lane] + red[192 + lane]);
    __syncthreads();
    red[t] = s2; __syncthreads();
    if (w == 0) atomicAdd(&stats[64 + lane], red[lane] + red[64 + lane] + red[128 + lane] + red[192 + lane]);
}

// ---- fused: BN(Y)+ReLU -> GEMM2 -> ReLU -> Hout(bf16); Yf += Hout @ Wj --
__global__ __launch_bounds__(TPB, 3)
void k_layerB(const float* __restrict__ Y, const float* __restrict__ stats,
              const float* __restrict__ g, const float* __restrict__ bt,
              const float* __restrict__ W2, const float* __restrict__ b2,
              const float* __restrict__ Wj,
              u16* __restrict__ Hout, float* __restrict__ Yf,
              float* __restrict__ stats5, int N, int rowsPerWave, int doHead) {
    int t = threadIdx.x;
    int lane = t & 63, w = t >> 6;
    float wc2[F], wcj[F];
#pragma unroll
    for (int f = 0; f < F; ++f) { wc2[f] = W2[f * F + lane]; wcj[f] = Wj[f * F + lane]; }
    float mu = stats[lane] / (float)N;
    float var = stats[64 + lane] / (float)N - mu * mu;
    float rs = rsqrtf(var + BN_EPS);
    float sc = rs * g[lane];
    float sh = bt[lane] - mu * sc;
    float bj = b2[lane];
    int row0 = (blockIdx.x * 4 + w) * rowsPerWave;
    float s1 = 0.f, s2 = 0.f;
    for (int r = 0; r < rowsPerWave; ++r) {
        int row = row0 + r;
        if (row >= N) break;
        float v = fmaxf(Y[(size_t)row * F + lane] * sc + sh, 0.f);
        float acc = bj;
#pragma unroll
        for (int f = 0; f < F; ++f) acc += lane_bcast(v, f) * wc2[f];
        float hv = fmaxf(acc, 0.f);
        Hout[(size_t)row * F + lane] = f2bf(hv);
        float yf = Yf[(size_t)row * F + lane];
#pragma unroll
        for (int f = 0; f < F; ++f) yf += lane_bcast(hv, f) * wcj[f];
        Yf[(size_t)row * F + lane] = yf;
        if (doHead) { s1 += yf; s2 += yf * yf; }
    }
    if (doHead) {
        __shared__ float red[TPB];
        red[t] = s1; __syncthreads();
        if (w == 0) atomicAdd(&stats5[lane], red[lane] + red[64 + lane] + red[128 + lane] + red[192 + lane]);
        __syncthreads();
        red[t] = s2; __syncthreads();
        if (w == 0) atomicAdd(&stats5[64 + lane], red[lane] + red[64 + lane] + red[128 + lane] + red[192 + lane]);
    }
}

// ---- head: BN(Yf)+ReLU -> @mlpW2+b2 -> pooled add into out[graph] -------
__global__ __launch_bounds__(TPB, 4)
void k_final(const float* __restrict__ Yf, const float* __restrict__ stats,
             const float* __restrict__ g, const float* __restrict__ bt,
             const float* __restrict__ W2, const float* __restrict__ b2,
             const int* __restrict__ batch, float* __restrict__ out,
             int N, int rowsPerWave) {
    int t = threadIdx.x;
    int lane = t & 63, w = t >> 6;
    float wcol[F];
#pragma unroll
    for (int f = 0; f < F; ++f) wcol[f] = W2[f * F + lane];
    float mu = stats[lane] / (float)N;
    float var = stats[64 + lane] / (float)N - mu * mu;
    float rs = rsqrtf(var + BN_EPS);
    float sc = rs * g[lane];
    float sh = bt[lane] - mu * sc;
    float bj = b2[lane];
    int row0 = (blockIdx.x * 4 + w) * rowsPerWave;
    int curg = -1;
    float accg = 0.f;
    for (int r = 0; r < rowsPerWave; ++r) {
        int row = row0 + r;
        if (row >= N) break;
        float v = fmaxf(Yf[(size_t)row * F + lane] * sc + sh, 0.f);
        float acc = bj;
#pragma unroll
        for (int f = 0; f < F; ++f) acc += lane_bcast(v, f) * wcol[f];
        int gid = batch[row];
        if (gid != curg) {
            if (curg >= 0) atomicAdd(&out[(size_t)curg * F + lane], accg);
            curg = gid;
            accg = 0.f;
        }
        accg += acc;
    }
    if (curg >= 0) atomicAdd(&out[(size_t)curg * F + lane], accg);
}

// ---- launcher -----------------------------------------------------------

extern "C" void kernel_launch(void* const* d_in, const int* in_sizes, int n_in,
                              void* d_out, int out_size, void* d_ws, size_t ws_size,
                              hipStream_t stream) {
    const float* x      = (const float*)d_in[0];
    const int*   ei     = (const int*)d_in[1];
    const int*   batch  = (const int*)d_in[2];
    const float* convW1 = (const float*)d_in[3];
    const float* convb1 = (const float*)d_in[4];
    const float* convg  = (const float*)d_in[5];
    const float* convbt = (const float*)d_in[6];
    const float* convW2 = (const float*)d_in[7];
    const float* convb2 = (const float*)d_in[8];
    const float* mlpW1  = (const float*)d_in[9];
    const float* mlpb1  = (const float*)d_in[10];
    const float* mlpg   = (const float*)d_in[11];
    const float* mlpbt  = (const float*)d_in[12];
    const float* mlpW2  = (const float*)d_in[13];
    const float* mlpb2  = (const float*)d_in[14];

    const int N = in_sizes[0] / F;             // 50000
    const int E = in_sizes[1] / 2;             // 800000
    const int L = in_sizes[3] / (F * F);       // 5

    const int* src = ei;
    const int* dst = ei + E;

    char* w = (char*)d_ws;
    size_t off = 0;
    auto alloc = [&](size_t bytes) {
        void* p = w + off;
        off = (off + bytes + 255) & ~(size_t)255;
        return p;
    };
    u16*   x16     = (u16*)alloc((size_t)N * F * 2);
    u16*   hA16    = (u16*)alloc((size_t)N * F * 2);
    u16*   hB16    = (u16*)alloc((size_t)N * F * 2);
    float* Ytmp    = (float*)alloc((size_t)N * F * 4);
    float* Yf      = (float*)alloc((size_t)N * F * 4);
    int*   deg     = (int*)alloc((size_t)N * 4);
    int*   offs    = (int*)alloc((size_t)(N + 1) * 4);
    int*   cursor  = (int*)alloc((size_t)N * 4);
    int*   csr_src = (int*)alloc((size_t)E * 4);
    int*   part    = (int*)alloc((size_t)SCAN_B * 4);
    float* stats   = (float*)alloc((size_t)(L + 1) * 128 * 4);
    int*   ctrs    = (int*)alloc((size_t)8 * 4);       // per-layer work counters

    hipMemsetAsync(deg, 0, (size_t)N * 4, stream);
    hipMemsetAsync(stats, 0, (size_t)(L + 1) * 128 * 4, stream);
    hipMemsetAsync(ctrs, 0, (size_t)8 * 4, stream);
    hipMemsetAsync(d_out, 0, (size_t)out_size * 4, stream);

    const int edgeBlocks = (E + TPB - 1) / TPB;

    k_hist<<<edgeBlocks, TPB, 0, stream>>>(dst, deg, E);
    k_scan_part<<<SCAN_B, TPB, 0, stream>>>(deg, part, N);
    k_scan_apply<<<SCAN_B, TPB, 0, stream>>>(deg, part, offs, cursor, N);
    k_fill<<<edgeBlocks, TPB, 0, stream>>>(src, dst, cursor, csr_src, E);

    const int RPW   = 8;
    const int RPW_F = 16;
    const int blocksA = 1536;                  // persistent: 6 blocks/CU
    const int blocksD = (N + 4 * RPW - 1) / (4 * RPW);
    const int blocksF = (N + 4 * RPW_F - 1) / (4 * RPW_F);

    // fused bf16-convert + JK-init (reads x once)
    k_prep<<<blocksD, TPB, 0, stream>>>(x, x16, mlpW1, mlpb1, Yf, N, RPW);

    const u16* h_cur = x16;
    for (int l = 0; l < L; ++l) {
        u16* h_next = (l & 1) ? hB16 : hA16;
        k_gather_gemm<<<blocksA, TPB, 0, stream>>>(h_cur, offs, csr_src,
                                                   convW1 + l * F * F, convb1 + l * F,
                                                   Ytmp, stats + l * 128, ctrs + l, N);
        k_layerB<<<blocksD, TPB, 0, stream>>>(Ytmp, stats + l * 128,
                                              convg + l * F, convbt + l * F,
                                              convW2 + l * F * F, convb2 + l * F,
                                              mlpW1 + (l + 1) * F * F,
                                              h_next, Yf, stats + L * 128,
                                              N, RPW, l == L - 1);
        h_cur = h_next;
    }

    k_final<<<blocksF, TPB, 0, stream>>>(Yf, stats + L * 128, mlpg, mlpbt,
                                         mlpW2, mlpb2, batch, (float*)d_out, N, RPW_F);
}

// Round 17
// 776.747 us; speedup vs baseline: 1.9926x; 1.9926x over previous
//
#include <hip/hip_runtime.h>

#define F 64
#define TPB 256
#define SCAN_B 64
#define BN_EPS 1e-5f

typedef unsigned short u16;

__device__ __forceinline__ float lane_bcast(float v, int l) {
    return __int_as_float(__builtin_amdgcn_readlane(__float_as_int(v), l));
}
__device__ __forceinline__ int lane_bcast_i(int v, int l) {
    return __builtin_amdgcn_readlane(v, l);
}
__device__ __forceinline__ float bf2f(u16 u) {
    return __uint_as_float(((unsigned int)u) << 16);
}
__device__ __forceinline__ u16 f2bf(float f) {
    unsigned int u = __float_as_uint(f);
    unsigned int r = (u + 0x7fffu + ((u >> 16) & 1u)) >> 16;   // RNE
    return (u16)r;
}

// ---- CSR build ----------------------------------------------------------

__global__ __launch_bounds__(TPB) void k_hist(const int* __restrict__ dst,
                                              int* __restrict__ deg, int E) {
    int e = blockIdx.x * blockDim.x + threadIdx.x;
    if (e < E) atomicAdd(&deg[dst[e]], 1);
}

__global__ __launch_bounds__(TPB) void k_scan_part(const int* __restrict__ deg,
                                                   int* __restrict__ part, int N) {
    __shared__ int red[TPB];
    int chunk = (N + SCAN_B - 1) / SCAN_B;
    int lo = blockIdx.x * chunk, hi = min(lo + chunk, N);
    int t = threadIdx.x;
    int s = 0;
    for (int i = lo + t; i < hi; i += TPB) s += deg[i];
    red[t] = s; __syncthreads();
    for (int d = TPB / 2; d > 0; d >>= 1) {
        if (t < d) red[t] += red[t + d];
        __syncthreads();
    }
    if (t == 0) part[blockIdx.x] = red[0];
}

__global__ __launch_bounds__(TPB) void k_scan_apply(const int* __restrict__ deg,
                                                    const int* __restrict__ part,
                                                    int* __restrict__ offs,
                                                    int* __restrict__ cursor, int N) {
    __shared__ int ts[TPB];
    __shared__ int pb_s;
    int t = threadIdx.x;
    ts[t] = (t < blockIdx.x) ? part[t] : 0;
    __syncthreads();
    for (int d = TPB / 2; d > 0; d >>= 1) {
        if (t < d) ts[t] += ts[t + d];
        __syncthreads();
    }
    if (t == 0) pb_s = ts[0];
    __syncthreads();
    int pbase = pb_s;
    __syncthreads();
    int chunk = (N + SCAN_B - 1) / SCAN_B;
    int sub = (chunk + TPB - 1) / TPB;
    int lo = blockIdx.x * chunk;
    int blockhi = min(lo + chunk, N);
    int mylo = min(lo + t * sub, blockhi);
    int myhi = min(mylo + sub, blockhi);
    int s = 0;
    for (int i = mylo; i < myhi; ++i) s += deg[i];
    ts[t] = s; __syncthreads();
    for (int d = 1; d < TPB; d <<= 1) {
        int a = (t >= d) ? ts[t - d] : 0;
        __syncthreads();
        ts[t] += a;
        __syncthreads();
    }
    int run = pbase + ts[t] - s;
    for (int i = mylo; i < myhi; ++i) {
        offs[i] = run; cursor[i] = run; run += deg[i];
    }
    if (blockIdx.x == SCAN_B - 1 && t == TPB - 1) offs[N] = pbase + ts[TPB - 1];
}

__global__ __launch_bounds__(TPB) void k_fill(const int* __restrict__ src,
                                              const int* __restrict__ dst,
                                              int* __restrict__ cursor,
                                              int* __restrict__ csr_src, int E) {
    int e = blockIdx.x * blockDim.x + threadIdx.x;
    if (e >= E) return;
    int pos = atomicAdd(&cursor[dst[e]], 1);
    csr_src[pos] = src[e];
}

// ---- prep: x16 = bf16(x); Yf = x @ Wj + bias (fused, reads x once) ------
__global__ __launch_bounds__(TPB, 4)
void k_prep(const float* __restrict__ x, u16* __restrict__ x16,
            const float* __restrict__ Wj, const float* __restrict__ bias,
            float* __restrict__ Yf, int N, int rowsPerWave) {
    int t = threadIdx.x;
    int lane = t & 63, w = t >> 6;
    float wcol[F];
#pragma unroll
    for (int f = 0; f < F; ++f) wcol[f] = Wj[f * F + lane];
    float bj = bias[lane];
    int row0 = (blockIdx.x * 4 + w) * rowsPerWave;
    for (int r = 0; r < rowsPerWave; ++r) {
        int row = row0 + r;
        if (row >= N) break;
        float v = x[(size_t)row * F + lane];
        x16[(size_t)row * F + lane] = f2bf(v);
        float acc = bj;
#pragma unroll
        for (int f = 0; f < F; ++f) acc += lane_bcast(v, f) * wcol[f];
        Yf[(size_t)row * F + lane] = acc;
    }
}

// ---- fused gather + GEMM1 + BN stats (R15 structure; Y stored bf16) -----
__global__ __launch_bounds__(TPB, 8)
void k_gather_gemm(const u16* __restrict__ h, const int* __restrict__ offs,
                   const int* __restrict__ csr,
                   const float* __restrict__ W, const float* __restrict__ bias,
                   u16* __restrict__ Y16, float* __restrict__ stats,
                   int N, int nodesPerWave) {
    __shared__ float Wl[F * F];
    int t = threadIdx.x;
    int lane = t & 63, w = t >> 6;
    for (int i = t; i < F * F; i += TPB) Wl[i] = W[i];
    __syncthreads();
    float bj = bias[lane];
    int node0 = (blockIdx.x * 4 + w) * nodesPerWave;
    int off_l = 0;
    if (lane <= nodesPerWave) off_l = offs[min(node0 + lane, N)];
    float s1 = 0.f, s2 = 0.f;
    int start_n = lane_bcast_i(off_l, 0);
    int end_n   = lane_bcast_i(off_l, 1);
    int cnt_n   = min(end_n - start_n, 64);
    int idx_n   = (lane < cnt_n) ? csr[start_n + lane] : 0;
    for (int r = 0; r < nodesPerWave; ++r) {
        int node = node0 + r;
        if (node >= N) break;
        int start = start_n, end = end_n, cnt = cnt_n, idx = idx_n;
        if (r + 1 < nodesPerWave) {
            start_n = lane_bcast_i(off_l, r + 1);
            end_n   = lane_bcast_i(off_l, r + 2);
            cnt_n   = min(end_n - start_n, 64);
            idx_n   = (lane < cnt_n) ? csr[start_n + lane] : 0;
        }
        float agg = bf2f(h[(size_t)node * F + lane]);    // GIN self term (eps=0)
        {
            int k = 0;
            for (; k + 16 <= cnt; k += 16) {
                float vv[16];
#pragma unroll
                for (int u = 0; u < 16; ++u)
                    vv[u] = bf2f(h[(size_t)lane_bcast_i(idx, k + u) * F + lane]);
                float sA = 0.f, sB = 0.f, sC = 0.f, sD = 0.f;
#pragma unroll
                for (int u = 0; u < 4; ++u) {
                    sA += vv[u]; sB += vv[4 + u]; sC += vv[8 + u]; sD += vv[12 + u];
                }
                agg += (sA + sB) + (sC + sD);
            }
            for (; k + 4 <= cnt; k += 4) {
                float v0 = bf2f(h[(size_t)lane_bcast_i(idx, k)     * F + lane]);
                float v1 = bf2f(h[(size_t)lane_bcast_i(idx, k + 1) * F + lane]);
                float v2 = bf2f(h[(size_t)lane_bcast_i(idx, k + 2) * F + lane]);
                float v3 = bf2f(h[(size_t)lane_bcast_i(idx, k + 3) * F + lane]);
                agg += (v0 + v1) + (v2 + v3);
            }
            for (; k < cnt; ++k)
                agg += bf2f(h[(size_t)lane_bcast_i(idx, k) * F + lane]);
        }
        for (int base = start + 64; base < end; base += 64) {
            int c2 = end - base; if (c2 > 64) c2 = 64;
            int idx2 = (lane < c2) ? csr[base + lane] : 0;
            int k = 0;
            for (; k + 4 <= c2; k += 4) {
                float v0 = bf2f(h[(size_t)lane_bcast_i(idx2, k)     * F + lane]);
                float v1 = bf2f(h[(size_t)lane_bcast_i(idx2, k + 1) * F + lane]);
                float v2 = bf2f(h[(size_t)lane_bcast_i(idx2, k + 2) * F + lane]);
                float v3 = bf2f(h[(size_t)lane_bcast_i(idx2, k + 3) * F + lane]);
                agg += (v0 + v1) + (v2 + v3);
            }
            for (; k < c2; ++k)
                agg += bf2f(h[(size_t)lane_bcast_i(idx2, k) * F + lane]);
        }
        float acc = bj;
#pragma unroll
        for (int f = 0; f < F; ++f) acc += lane_bcast(agg, f) * Wl[f * F + lane];
        Y16[(size_t)node * F + lane] = f2bf(acc);
        s1 += acc;
        s2 += acc * acc;
    }
    __shared__ float red[TPB];
    red[t] = s1; __syncthreads();
    if (w == 0) atomicAdd(&stats[lane], red[lane] + red[64 + lane] + red[128 + lane] + red[192 + lane]);
    __syncthreads();
    red[t] = s2; __syncthreads();
    if (w == 0) atomicAdd(&stats[64 + lane], red[lane] + red[64 + lane] + red[128 + lane] + red[192 + lane]);
}

// ---- fused: BN(Y16)+ReLU -> GEMM2 -> ReLU -> Hout(bf16); Yf += Hout @ Wj
// LDS-broadcast GEMM: row vector in wave-private LDS (DS in-order per wave,
// no barrier -- R4-verified pattern); 1 ds_read_b128 + 4 v_fmac per 4 MACs
// halves the VALU cost vs readlane+fmac.
__global__ __launch_bounds__(TPB, 3)
void k_layerB(const u16* __restrict__ Y16, const float* __restrict__ stats,
              const float* __restrict__ g, const float* __restrict__ bt,
              const float* __restrict__ W2, const float* __restrict__ b2,
              const float* __restrict__ Wj,
              u16* __restrict__ Hout, float* __restrict__ Yf,
              float* __restrict__ stats5, int N, int rowsPerWave, int doHead) {
    __shared__ float vbuf[4][F];
    __shared__ float red[TPB];
    int t = threadIdx.x;
    int lane = t & 63, w = t >> 6;
    float wc2[F], wcj[F];
#pragma unroll
    for (int f = 0; f < F; ++f) { wc2[f] = W2[f * F + lane]; wcj[f] = Wj[f * F + lane]; }
    float mu = stats[lane] / (float)N;
    float var = stats[64 + lane] / (float)N - mu * mu;
    float rs = rsqrtf(var + BN_EPS);
    float sc = rs * g[lane];
    float sh = bt[lane] - mu * sc;
    float bj = b2[lane];
    const float4* vb4 = (const float4*)vbuf[w];
    int row0 = (blockIdx.x * 4 + w) * rowsPerWave;
    float s1 = 0.f, s2 = 0.f;
    for (int r = 0; r < rowsPerWave; ++r) {
        int row = row0 + r;
        if (row >= N) break;
        float v = fmaxf(bf2f(Y16[(size_t)row * F + lane]) * sc + sh, 0.f);
        vbuf[w][lane] = v;                 // ds_write; DS in-order per wave
        float acc = bj;
#pragma unroll
        for (int gi = 0; gi < 16; ++gi) {
            float4 q = vb4[gi];            // ds_read_b128, same-addr broadcast
            acc += q.x * wc2[4 * gi] + q.y * wc2[4 * gi + 1]
                 + q.z * wc2[4 * gi + 2] + q.w * wc2[4 * gi + 3];
        }
        float hv = fmaxf(acc, 0.f);
        Hout[(size_t)row * F + lane] = f2bf(hv);
        vbuf[w][lane] = hv;                // overwrite after all reads (in-order)
        float yf = Yf[(size_t)row * F + lane];
#pragma unroll
        for (int gi = 0; gi < 16; ++gi) {
            float4 q = vb4[gi];
            yf += q.x * wcj[4 * gi] + q.y * wcj[4 * gi + 1]
                + q.z * wcj[4 * gi + 2] + q.w * wcj[4 * gi + 3];
        }
        Yf[(size_t)row * F + lane] = yf;
        if (doHead) { s1 += yf; s2 += yf * yf; }
    }
    if (doHead) {
        red[t] = s1; __syncthreads();
        if (w == 0) atomicAdd(&stats5[lane], red[lane] + red[64 + lane] + red[128 + lane] + red[192 + lane]);
        __syncthreads();
        red[t] = s2; __syncthreads();
        if (w == 0) atomicAdd(&stats5[64 + lane], red[lane] + red[64 + lane] + red[128 + lane] + red[192 + lane]);
    }
}

// ---- head: BN(Yf)+ReLU -> @mlpW2+b2 -> pooled add into out[graph] -------
__global__ __launch_bounds__(TPB, 4)
void k_final(const float* __restrict__ Yf, const float* __restrict__ stats,
             const float* __restrict__ g, const float* __restrict__ bt,
             const float* __restrict__ W2, const float* __restrict__ b2,
             const int* __restrict__ batch, float* __restrict__ out,
             int N, int rowsPerWave) {
    int t = threadIdx.x;
    int lane = t & 63, w = t >> 6;
    float wcol[F];
#pragma unroll
    for (int f = 0; f < F; ++f) wcol[f] = W2[f * F + lane];
    float mu = stats[lane] / (float)N;
    float var = stats[64 + lane] / (float)N - mu * mu;
    float rs = rsqrtf(var + BN_EPS);
    float sc = rs * g[lane];
    float sh = bt[lane] - mu * sc;
    float bj = b2[lane];
    int row0 = (blockIdx.x * 4 + w) * rowsPerWave;
    int curg = -1;
    float accg = 0.f;
    for (int r = 0; r < rowsPerWave; ++r) {
        int row = row0 + r;
        if (row >= N) break;
        float v = fmaxf(Yf[(size_t)row * F + lane] * sc + sh, 0.f);
        float acc = bj;
#pragma unroll
        for (int f = 0; f < F; ++f) acc += lane_bcast(v, f) * wcol[f];
        int gid = batch[row];
        if (gid != curg) {
            if (curg >= 0) atomicAdd(&out[(size_t)curg * F + lane], accg);
            curg = gid;
            accg = 0.f;
        }
        accg += acc;
    }
    if (curg >= 0) atomicAdd(&out[(size_t)curg * F + lane], accg);
}

// ---- launcher -----------------------------------------------------------

extern "C" void kernel_launch(void* const* d_in, const int* in_sizes, int n_in,
                              void* d_out, int out_size, void* d_ws, size_t ws_size,
                              hipStream_t stream) {
    const float* x      = (const float*)d_in[0];
    const int*   ei     = (const int*)d_in[1];
    const int*   batch  = (const int*)d_in[2];
    const float* convW1 = (const float*)d_in[3];
    const float* convb1 = (const float*)d_in[4];
    const float* convg  = (const float*)d_in[5];
    const float* convbt = (const float*)d_in[6];
    const float* convW2 = (const float*)d_in[7];
    const float* convb2 = (const float*)d_in[8];
    const float* mlpW1  = (const float*)d_in[9];
    const float* mlpb1  = (const float*)d_in[10];
    const float* mlpg   = (const float*)d_in[11];
    const float* mlpbt  = (const float*)d_in[12];
    const float* mlpW2  = (const float*)d_in[13];
    const float* mlpb2  = (const float*)d_in[14];

    const int N = in_sizes[0] / F;             // 50000
    const int E = in_sizes[1] / 2;             // 800000
    const int L = in_sizes[3] / (F * F);       // 5

    const int* src = ei;
    const int* dst = ei + E;

    char* w = (char*)d_ws;
    size_t off = 0;
    auto alloc = [&](size_t bytes) {
        void* p = w + off;
        off = (off + bytes + 255) & ~(size_t)255;
        return p;
    };
    u16*   x16     = (u16*)alloc((size_t)N * F * 2);
    u16*   hA16    = (u16*)alloc((size_t)N * F * 2);
    u16*   hB16    = (u16*)alloc((size_t)N * F * 2);
    u16*   Ytmp16  = (u16*)alloc((size_t)N * F * 2);
    float* Yf      = (float*)alloc((size_t)N * F * 4);
    int*   deg     = (int*)alloc((size_t)N * 4);
    int*   offs    = (int*)alloc((size_t)(N + 1) * 4);
    int*   cursor  = (int*)alloc((size_t)N * 4);
    int*   csr_src = (int*)alloc((size_t)E * 4);
    int*   part    = (int*)alloc((size_t)SCAN_B * 4);
    float* stats   = (float*)alloc((size_t)(L + 1) * 128 * 4);

    hipMemsetAsync(deg, 0, (size_t)N * 4, stream);
    hipMemsetAsync(stats, 0, (size_t)(L + 1) * 128 * 4, stream);
    hipMemsetAsync(d_out, 0, (size_t)out_size * 4, stream);

    const int edgeBlocks = (E + TPB - 1) / TPB;

    k_hist<<<edgeBlocks, TPB, 0, stream>>>(dst, deg, E);
    k_scan_part<<<SCAN_B, TPB, 0, stream>>>(deg, part, N);
    k_scan_apply<<<SCAN_B, TPB, 0, stream>>>(deg, part, offs, cursor, N);
    k_fill<<<edgeBlocks, TPB, 0, stream>>>(src, dst, cursor, csr_src, E);

    const int NPW_A = 8;     // R12/R15 proven config; 1563 blocks
    const int RPW   = 8;
    const int RPW_F = 16;
    const int blocksA = (N + 4 * NPW_A - 1) / (4 * NPW_A);
    const int blocksD = (N + 4 * RPW - 1) / (4 * RPW);
    const int blocksF = (N + 4 * RPW_F - 1) / (4 * RPW_F);

    // fused bf16-convert + JK-init (reads x once)
    k_prep<<<blocksD, TPB, 0, stream>>>(x, x16, mlpW1, mlpb1, Yf, N, RPW);

    const u16* h_cur = x16;
    for (int l = 0; l < L; ++l) {
        u16* h_next = (l & 1) ? hB16 : hA16;
        k_gather_gemm<<<blocksA, TPB, 0, stream>>>(h_cur, offs, csr_src,
                                                   convW1 + l * F * F, convb1 + l * F,
                                                   Ytmp16, stats + l * 128, N, NPW_A);
        k_layerB<<<blocksD, TPB, 0, stream>>>(Ytmp16, stats + l * 128,
                                              convg + l * F, convbt + l * F,
                                              convW2 + l * F * F, convb2 + l * F,
                                              mlpW1 + (l + 1) * F * F,
                                              h_next, Yf, stats + L * 128,
                                              N, RPW, l == L - 1);
        h_cur = h_next;
    }

    k_final<<<blocksF, TPB, 0, stream>>>(Yf, stats + L * 128, mlpg, mlpbt,
                                         mlpW2, mlpb2, batch, (float*)d_out, N, RPW_F);
}

// Round 18
// 749.044 us; speedup vs baseline: 2.0663x; 1.0370x over previous
//
#include <hip/hip_runtime.h>

#define F 64
#define TPB 256
#define SCAN_B 64
#define BN_EPS 1e-5f

typedef unsigned short u16;

__device__ __forceinline__ float lane_bcast(float v, int l) {
    return __int_as_float(__builtin_amdgcn_readlane(__float_as_int(v), l));
}
__device__ __forceinline__ int lane_bcast_i(int v, int l) {
    return __builtin_amdgcn_readlane(v, l);
}
__device__ __forceinline__ float bf2f(u16 u) {
    return __uint_as_float(((unsigned int)u) << 16);
}
__device__ __forceinline__ u16 f2bf(float f) {
    unsigned int u = __float_as_uint(f);
    unsigned int r = (u + 0x7fffu + ((u >> 16) & 1u)) >> 16;   // RNE
    return (u16)r;
}

// ---- CSR build ----------------------------------------------------------

__global__ __launch_bounds__(TPB) void k_hist(const int* __restrict__ dst,
                                              int* __restrict__ deg, int E) {
    int e = blockIdx.x * blockDim.x + threadIdx.x;
    if (e < E) atomicAdd(&deg[dst[e]], 1);
}

__global__ __launch_bounds__(TPB) void k_scan_part(const int* __restrict__ deg,
                                                   int* __restrict__ part, int N) {
    __shared__ int red[TPB];
    int chunk = (N + SCAN_B - 1) / SCAN_B;
    int lo = blockIdx.x * chunk, hi = min(lo + chunk, N);
    int t = threadIdx.x;
    int s = 0;
    for (int i = lo + t; i < hi; i += TPB) s += deg[i];
    red[t] = s; __syncthreads();
    for (int d = TPB / 2; d > 0; d >>= 1) {
        if (t < d) red[t] += red[t + d];
        __syncthreads();
    }
    if (t == 0) part[blockIdx.x] = red[0];
}

__global__ __launch_bounds__(TPB) void k_scan_apply(const int* __restrict__ deg,
                                                    const int* __restrict__ part,
                                                    int* __restrict__ offs,
                                                    int* __restrict__ cursor, int N) {
    __shared__ int ts[TPB];
    __shared__ int pb_s;
    int t = threadIdx.x;
    ts[t] = (t < blockIdx.x) ? part[t] : 0;
    __syncthreads();
    for (int d = TPB / 2; d > 0; d >>= 1) {
        if (t < d) ts[t] += ts[t + d];
        __syncthreads();
    }
    if (t == 0) pb_s = ts[0];
    __syncthreads();
    int pbase = pb_s;
    __syncthreads();
    int chunk = (N + SCAN_B - 1) / SCAN_B;
    int sub = (chunk + TPB - 1) / TPB;
    int lo = blockIdx.x * chunk;
    int blockhi = min(lo + chunk, N);
    int mylo = min(lo + t * sub, blockhi);
    int myhi = min(mylo + sub, blockhi);
    int s = 0;
    for (int i = mylo; i < myhi; ++i) s += deg[i];
    ts[t] = s; __syncthreads();
    for (int d = 1; d < TPB; d <<= 1) {
        int a = (t >= d) ? ts[t - d] : 0;
        __syncthreads();
        ts[t] += a;
        __syncthreads();
    }
    int run = pbase + ts[t] - s;
    for (int i = mylo; i < myhi; ++i) {
        offs[i] = run; cursor[i] = run; run += deg[i];
    }
    if (blockIdx.x == SCAN_B - 1 && t == TPB - 1) offs[N] = pbase + ts[TPB - 1];
}

__global__ __launch_bounds__(TPB) void k_fill(const int* __restrict__ src,
                                              const int* __restrict__ dst,
                                              int* __restrict__ cursor,
                                              int* __restrict__ csr_src, int E) {
    int e = blockIdx.x * blockDim.x + threadIdx.x;
    if (e >= E) return;
    int pos = atomicAdd(&cursor[dst[e]], 1);
    csr_src[pos] = src[e];
}

// ---- prep: x16 = bf16(x); Yf = x @ Wj + bias (fused, reads x once) ------
__global__ __launch_bounds__(TPB, 4)
void k_prep(const float* __restrict__ x, u16* __restrict__ x16,
            const float* __restrict__ Wj, const float* __restrict__ bias,
            float* __restrict__ Yf, int N, int rowsPerWave) {
    int t = threadIdx.x;
    int lane = t & 63, w = t >> 6;
    float wcol[F];
#pragma unroll
    for (int f = 0; f < F; ++f) wcol[f] = Wj[f * F + lane];
    float bj = bias[lane];
    int row0 = (blockIdx.x * 4 + w) * rowsPerWave;
    for (int r = 0; r < rowsPerWave; ++r) {
        int row = row0 + r;
        if (row >= N) break;
        float v = x[(size_t)row * F + lane];
        x16[(size_t)row * F + lane] = f2bf(v);
        float acc = bj;
#pragma unroll
        for (int f = 0; f < F; ++f) acc += lane_bcast(v, f) * wcol[f];
        Yf[(size_t)row * F + lane] = acc;
    }
}

// ---- fused gather + GEMM1 + BN stats (R15 structure; Y stored bf16) -----
__global__ __launch_bounds__(TPB, 8)
void k_gather_gemm(const u16* __restrict__ h, const int* __restrict__ offs,
                   const int* __restrict__ csr,
                   const float* __restrict__ W, const float* __restrict__ bias,
                   u16* __restrict__ Y16, float* __restrict__ stats,
                   int N, int nodesPerWave) {
    __shared__ float Wl[F * F];
    int t = threadIdx.x;
    int lane = t & 63, w = t >> 6;
    for (int i = t; i < F * F; i += TPB) Wl[i] = W[i];
    __syncthreads();
    float bj = bias[lane];
    int node0 = (blockIdx.x * 4 + w) * nodesPerWave;
    int off_l = 0;
    if (lane <= nodesPerWave) off_l = offs[min(node0 + lane, N)];
    float s1 = 0.f, s2 = 0.f;
    int start_n = lane_bcast_i(off_l, 0);
    int end_n   = lane_bcast_i(off_l, 1);
    int cnt_n   = min(end_n - start_n, 64);
    int idx_n   = (lane < cnt_n) ? csr[start_n + lane] : 0;
    for (int r = 0; r < nodesPerWave; ++r) {
        int node = node0 + r;
        if (node >= N) break;
        int start = start_n, end = end_n, cnt = cnt_n, idx = idx_n;
        if (r + 1 < nodesPerWave) {
            start_n = lane_bcast_i(off_l, r + 1);
            end_n   = lane_bcast_i(off_l, r + 2);
            cnt_n   = min(end_n - start_n, 64);
            idx_n   = (lane < cnt_n) ? csr[start_n + lane] : 0;
        }
        float agg = bf2f(h[(size_t)node * F + lane]);    // GIN self term (eps=0)
        {
            int k = 0;
            for (; k + 16 <= cnt; k += 16) {
                float vv[16];
#pragma unroll
                for (int u = 0; u < 16; ++u)
                    vv[u] = bf2f(h[(size_t)lane_bcast_i(idx, k + u) * F + lane]);
                float sA = 0.f, sB = 0.f, sC = 0.f, sD = 0.f;
#pragma unroll
                for (int u = 0; u < 4; ++u) {
                    sA += vv[u]; sB += vv[4 + u]; sC += vv[8 + u]; sD += vv[12 + u];
                }
                agg += (sA + sB) + (sC + sD);
            }
            for (; k + 4 <= cnt; k += 4) {
                float v0 = bf2f(h[(size_t)lane_bcast_i(idx, k)     * F + lane]);
                float v1 = bf2f(h[(size_t)lane_bcast_i(idx, k + 1) * F + lane]);
                float v2 = bf2f(h[(size_t)lane_bcast_i(idx, k + 2) * F + lane]);
                float v3 = bf2f(h[(size_t)lane_bcast_i(idx, k + 3) * F + lane]);
                agg += (v0 + v1) + (v2 + v3);
            }
            for (; k < cnt; ++k)
                agg += bf2f(h[(size_t)lane_bcast_i(idx, k) * F + lane]);
        }
        for (int base = start + 64; base < end; base += 64) {
            int c2 = end - base; if (c2 > 64) c2 = 64;
            int idx2 = (lane < c2) ? csr[base + lane] : 0;
            int k = 0;
            for (; k + 4 <= c2; k += 4) {
                float v0 = bf2f(h[(size_t)lane_bcast_i(idx2, k)     * F + lane]);
                float v1 = bf2f(h[(size_t)lane_bcast_i(idx2, k + 1) * F + lane]);
                float v2 = bf2f(h[(size_t)lane_bcast_i(idx2, k + 2) * F + lane]);
                float v3 = bf2f(h[(size_t)lane_bcast_i(idx2, k + 3) * F + lane]);
                agg += (v0 + v1) + (v2 + v3);
            }
            for (; k < c2; ++k)
                agg += bf2f(h[(size_t)lane_bcast_i(idx2, k) * F + lane]);
        }
        float acc = bj;
#pragma unroll
        for (int f = 0; f < F; ++f) acc += lane_bcast(agg, f) * Wl[f * F + lane];
        Y16[(size_t)node * F + lane] = f2bf(acc);
        s1 += acc;
        s2 += acc * acc;
    }
    __shared__ float red[TPB];
    red[t] = s1; __syncthreads();
    if (w == 0) atomicAdd(&stats[lane], red[lane] + red[64 + lane] + red[128 + lane] + red[192 + lane]);
    __syncthreads();
    red[t] = s2; __syncthreads();
    if (w == 0) atomicAdd(&stats[64 + lane], red[lane] + red[64 + lane] + red[128 + lane] + red[192 + lane]);
}

// ---- fused: BN(Y16)+ReLU -> GEMM2 -> ReLU -> Hout(bf16); Yf += Hout @ Wj
// R15 readlane GEMM body (LDS-broadcast variant regressed in R17: DS-latency
// stalls at 3 waves/SIMD beat the VALU savings). Input Y is bf16.
__global__ __launch_bounds__(TPB, 3)
void k_layerB(const u16* __restrict__ Y16, const float* __restrict__ stats,
              const float* __restrict__ g, const float* __restrict__ bt,
              const float* __restrict__ W2, const float* __restrict__ b2,
              const float* __restrict__ Wj,
              u16* __restrict__ Hout, float* __restrict__ Yf,
              float* __restrict__ stats5, int N, int rowsPerWave, int doHead) {
    int t = threadIdx.x;
    int lane = t & 63, w = t >> 6;
    float wc2[F], wcj[F];
#pragma unroll
    for (int f = 0; f < F; ++f) { wc2[f] = W2[f * F + lane]; wcj[f] = Wj[f * F + lane]; }
    float mu = stats[lane] / (float)N;
    float var = stats[64 + lane] / (float)N - mu * mu;
    float rs = rsqrtf(var + BN_EPS);
    float sc = rs * g[lane];
    float sh = bt[lane] - mu * sc;
    float bj = b2[lane];
    int row0 = (blockIdx.x * 4 + w) * rowsPerWave;
    float s1 = 0.f, s2 = 0.f;
    for (int r = 0; r < rowsPerWave; ++r) {
        int row = row0 + r;
        if (row >= N) break;
        float v = fmaxf(bf2f(Y16[(size_t)row * F + lane]) * sc + sh, 0.f);
        float acc = bj;
#pragma unroll
        for (int f = 0; f < F; ++f) acc += lane_bcast(v, f) * wc2[f];
        float hv = fmaxf(acc, 0.f);
        Hout[(size_t)row * F + lane] = f2bf(hv);
        float yf = Yf[(size_t)row * F + lane];
#pragma unroll
        for (int f = 0; f < F; ++f) yf += lane_bcast(hv, f) * wcj[f];
        Yf[(size_t)row * F + lane] = yf;
        if (doHead) { s1 += yf; s2 += yf * yf; }
    }
    if (doHead) {
        __shared__ float red[TPB];
        red[t] = s1; __syncthreads();
        if (w == 0) atomicAdd(&stats5[lane], red[lane] + red[64 + lane] + red[128 + lane] + red[192 + lane]);
        __syncthreads();
        red[t] = s2; __syncthreads();
        if (w == 0) atomicAdd(&stats5[64 + lane], red[lane] + red[64 + lane] + red[128 + lane] + red[192 + lane]);
    }
}

// ---- head: BN(Yf)+ReLU -> @mlpW2+b2 -> pooled add into out[graph] -------
__global__ __launch_bounds__(TPB, 4)
void k_final(const float* __restrict__ Yf, const float* __restrict__ stats,
             const float* __restrict__ g, const float* __restrict__ bt,
             const float* __restrict__ W2, const float* __restrict__ b2,
             const int* __restrict__ batch, float* __restrict__ out,
             int N, int rowsPerWave) {
    int t = threadIdx.x;
    int lane = t & 63, w = t >> 6;
    float wcol[F];
#pragma unroll
    for (int f = 0; f < F; ++f) wcol[f] = W2[f * F + lane];
    float mu = stats[lane] / (float)N;
    float var = stats[64 + lane] / (float)N - mu * mu;
    float rs = rsqrtf(var + BN_EPS);
    float sc = rs * g[lane];
    float sh = bt[lane] - mu * sc;
    float bj = b2[lane];
    int row0 = (blockIdx.x * 4 + w) * rowsPerWave;
    int curg = -1;
    float accg = 0.f;
    for (int r = 0; r < rowsPerWave; ++r) {
        int row = row0 + r;
        if (row >= N) break;
        float v = fmaxf(Yf[(size_t)row * F + lane] * sc + sh, 0.f);
        float acc = bj;
#pragma unroll
        for (int f = 0; f < F; ++f) acc += lane_bcast(v, f) * wcol[f];
        int gid = batch[row];
        if (gid != curg) {
            if (curg >= 0) atomicAdd(&out[(size_t)curg * F + lane], accg);
            curg = gid;
            accg = 0.f;
        }
        accg += acc;
    }
    if (curg >= 0) atomicAdd(&out[(size_t)curg * F + lane], accg);
}

// ---- launcher -----------------------------------------------------------

extern "C" void kernel_launch(void* const* d_in, const int* in_sizes, int n_in,
                              void* d_out, int out_size, void* d_ws, size_t ws_size,
                              hipStream_t stream) {
    const float* x      = (const float*)d_in[0];
    const int*   ei     = (const int*)d_in[1];
    const int*   batch  = (const int*)d_in[2];
    const float* convW1 = (const float*)d_in[3];
    const float* convb1 = (const float*)d_in[4];
    const float* convg  = (const float*)d_in[5];
    const float* convbt = (const float*)d_in[6];
    const float* convW2 = (const float*)d_in[7];
    const float* convb2 = (const float*)d_in[8];
    const float* mlpW1  = (const float*)d_in[9];
    const float* mlpb1  = (const float*)d_in[10];
    const float* mlpg   = (const float*)d_in[11];
    const float* mlpbt  = (const float*)d_in[12];
    const float* mlpW2  = (const float*)d_in[13];
    const float* mlpb2  = (const float*)d_in[14];

    const int N = in_sizes[0] / F;             // 50000
    const int E = in_sizes[1] / 2;             // 800000
    const int L = in_sizes[3] / (F * F);       // 5

    const int* src = ei;
    const int* dst = ei + E;

    char* w = (char*)d_ws;
    size_t off = 0;
    auto alloc = [&](size_t bytes) {
        void* p = w + off;
        off = (off + bytes + 255) & ~(size_t)255;
        return p;
    };
    u16*   x16     = (u16*)alloc((size_t)N * F * 2);
    u16*   hA16    = (u16*)alloc((size_t)N * F * 2);
    u16*   hB16    = (u16*)alloc((size_t)N * F * 2);
    u16*   Ytmp16  = (u16*)alloc((size_t)N * F * 2);
    float* Yf      = (float*)alloc((size_t)N * F * 4);
    int*   deg     = (int*)alloc((size_t)N * 4);
    int*   offs    = (int*)alloc((size_t)(N + 1) * 4);
    int*   cursor  = (int*)alloc((size_t)N * 4);
    int*   csr_src = (int*)alloc((size_t)E * 4);
    int*   part    = (int*)alloc((size_t)SCAN_B * 4);
    float* stats   = (float*)alloc((size_t)(L + 1) * 128 * 4);

    hipMemsetAsync(deg, 0, (size_t)N * 4, stream);
    hipMemsetAsync(stats, 0, (size_t)(L + 1) * 128 * 4, stream);
    hipMemsetAsync(d_out, 0, (size_t)out_size * 4, stream);

    const int edgeBlocks = (E + TPB - 1) / TPB;

    k_hist<<<edgeBlocks, TPB, 0, stream>>>(dst, deg, E);
    k_scan_part<<<SCAN_B, TPB, 0, stream>>>(deg, part, N);
    k_scan_apply<<<SCAN_B, TPB, 0, stream>>>(deg, part, offs, cursor, N);
    k_fill<<<edgeBlocks, TPB, 0, stream>>>(src, dst, cursor, csr_src, E);

    const int NPW_A = 8;     // R12/R15 proven config; 1563 blocks
    const int RPW   = 8;
    const int RPW_F = 16;
    const int blocksA = (N + 4 * NPW_A - 1) / (4 * NPW_A);
    const int blocksD = (N + 4 * RPW - 1) / (4 * RPW);
    const int blocksF = (N + 4 * RPW_F - 1) / (4 * RPW_F);

    // fused bf16-convert + JK-init (reads x once)
    k_prep<<<blocksD, TPB, 0, stream>>>(x, x16, mlpW1, mlpb1, Yf, N, RPW);

    const u16* h_cur = x16;
    for (int l = 0; l < L; ++l) {
        u16* h_next = (l & 1) ? hB16 : hA16;
        k_gather_gemm<<<blocksA, TPB, 0, stream>>>(h_cur, offs, csr_src,
                                                   convW1 + l * F * F, convb1 + l * F,
                                                   Ytmp16, stats + l * 128, N, NPW_A);
        k_layerB<<<blocksD, TPB, 0, stream>>>(Ytmp16, stats + l * 128,
                                              convg + l * F, convbt + l * F,
                                              convW2 + l * F * F, convb2 + l * F,
                                              mlpW1 + (l + 1) * F * F,
                                              h_next, Yf, stats + L * 128,
                                              N, RPW, l == L - 1);
        h_cur = h_next;
    }

    k_final<<<blocksF, TPB, 0, stream>>>(Yf, stats + L * 128, mlpg, mlpbt,
                                         mlpW2, mlpb2, batch, (float*)d_out, N, RPW_F);
}

// Round 19
// 630.907 us; speedup vs baseline: 2.4532x; 1.1872x over previous
//
#include <hip/hip_runtime.h>

#define F 64
#define TPB 256
#define SCAN_B 64
#define BN_EPS 1e-5f

typedef unsigned short u16;
typedef __attribute__((ext_vector_type(8))) short v8s;
typedef __attribute__((ext_vector_type(4))) float v4f;

__device__ __forceinline__ float lane_bcast(float v, int l) {
    return __int_as_float(__builtin_amdgcn_readlane(__float_as_int(v), l));
}
__device__ __forceinline__ int lane_bcast_i(int v, int l) {
    return __builtin_amdgcn_readlane(v, l);
}
__device__ __forceinline__ float bf2f(u16 u) {
    return __uint_as_float(((unsigned int)u) << 16);
}
__device__ __forceinline__ u16 f2bf(float f) {
    unsigned int u = __float_as_uint(f);
    unsigned int r = (u + 0x7fffu + ((u >> 16) & 1u)) >> 16;   // RNE
    return (u16)r;
}

// ---- CSR build ----------------------------------------------------------

__global__ __launch_bounds__(TPB) void k_hist(const int* __restrict__ dst,
                                              int* __restrict__ deg, int E) {
    int e = blockIdx.x * blockDim.x + threadIdx.x;
    if (e < E) atomicAdd(&deg[dst[e]], 1);
}

__global__ __launch_bounds__(TPB) void k_scan_part(const int* __restrict__ deg,
                                                   int* __restrict__ part, int N) {
    __shared__ int red[TPB];
    int chunk = (N + SCAN_B - 1) / SCAN_B;
    int lo = blockIdx.x * chunk, hi = min(lo + chunk, N);
    int t = threadIdx.x;
    int s = 0;
    for (int i = lo + t; i < hi; i += TPB) s += deg[i];
    red[t] = s; __syncthreads();
    for (int d = TPB / 2; d > 0; d >>= 1) {
        if (t < d) red[t] += red[t + d];
        __syncthreads();
    }
    if (t == 0) part[blockIdx.x] = red[0];
}

__global__ __launch_bounds__(TPB) void k_scan_apply(const int* __restrict__ deg,
                                                    const int* __restrict__ part,
                                                    int* __restrict__ offs,
                                                    int* __restrict__ cursor, int N) {
    __shared__ int ts[TPB];
    __shared__ int pb_s;
    int t = threadIdx.x;
    ts[t] = (t < blockIdx.x) ? part[t] : 0;
    __syncthreads();
    for (int d = TPB / 2; d > 0; d >>= 1) {
        if (t < d) ts[t] += ts[t + d];
        __syncthreads();
    }
    if (t == 0) pb_s = ts[0];
    __syncthreads();
    int pbase = pb_s;
    __syncthreads();
    int chunk = (N + SCAN_B - 1) / SCAN_B;
    int sub = (chunk + TPB - 1) / TPB;
    int lo = blockIdx.x * chunk;
    int blockhi = min(lo + chunk, N);
    int mylo = min(lo + t * sub, blockhi);
    int myhi = min(mylo + sub, blockhi);
    int s = 0;
    for (int i = mylo; i < myhi; ++i) s += deg[i];
    ts[t] = s; __syncthreads();
    for (int d = 1; d < TPB; d <<= 1) {
        int a = (t >= d) ? ts[t - d] : 0;
        __syncthreads();
        ts[t] += a;
        __syncthreads();
    }
    int run = pbase + ts[t] - s;
    for (int i = mylo; i < myhi; ++i) {
        offs[i] = run; cursor[i] = run; run += deg[i];
    }
    if (blockIdx.x == SCAN_B - 1 && t == TPB - 1) offs[N] = pbase + ts[TPB - 1];
}

__global__ __launch_bounds__(TPB) void k_fill(const int* __restrict__ src,
                                              const int* __restrict__ dst,
                                              int* __restrict__ cursor,
                                              int* __restrict__ csr_src, int E) {
    int e = blockIdx.x * blockDim.x + threadIdx.x;
    if (e >= E) return;
    int pos = atomicAdd(&cursor[dst[e]], 1);
    csr_src[pos] = src[e];
}

// ---- prep: x16 = bf16(x); Yf = x @ Wj + bias (fused, reads x once) ------
__global__ __launch_bounds__(TPB, 4)
void k_prep(const float* __restrict__ x, u16* __restrict__ x16,
            const float* __restrict__ Wj, const float* __restrict__ bias,
            float* __restrict__ Yf, int N, int rowsPerWave) {
    int t = threadIdx.x;
    int lane = t & 63, w = t >> 6;
    float wcol[F];
#pragma unroll
    for (int f = 0; f < F; ++f) wcol[f] = Wj[f * F + lane];
    float bj = bias[lane];
    int row0 = (blockIdx.x * 4 + w) * rowsPerWave;
    for (int r = 0; r < rowsPerWave; ++r) {
        int row = row0 + r;
        if (row >= N) break;
        float v = x[(size_t)row * F + lane];
        x16[(size_t)row * F + lane] = f2bf(v);
        float acc = bj;
#pragma unroll
        for (int f = 0; f < F; ++f) acc += lane_bcast(v, f) * wcol[f];
        Yf[(size_t)row * F + lane] = acc;
    }
}

// ---- fused gather + GEMM1 + BN stats (R15 structure; Y stored bf16) -----
__global__ __launch_bounds__(TPB, 8)
void k_gather_gemm(const u16* __restrict__ h, const int* __restrict__ offs,
                   const int* __restrict__ csr,
                   const float* __restrict__ W, const float* __restrict__ bias,
                   u16* __restrict__ Y16, float* __restrict__ stats,
                   int N, int nodesPerWave) {
    __shared__ float Wl[F * F];
    int t = threadIdx.x;
    int lane = t & 63, w = t >> 6;
    for (int i = t; i < F * F; i += TPB) Wl[i] = W[i];
    __syncthreads();
    float bj = bias[lane];
    int node0 = (blockIdx.x * 4 + w) * nodesPerWave;
    int off_l = 0;
    if (lane <= nodesPerWave) off_l = offs[min(node0 + lane, N)];
    float s1 = 0.f, s2 = 0.f;
    int start_n = lane_bcast_i(off_l, 0);
    int end_n   = lane_bcast_i(off_l, 1);
    int cnt_n   = min(end_n - start_n, 64);
    int idx_n   = (lane < cnt_n) ? csr[start_n + lane] : 0;
    for (int r = 0; r < nodesPerWave; ++r) {
        int node = node0 + r;
        if (node >= N) break;
        int start = start_n, end = end_n, cnt = cnt_n, idx = idx_n;
        if (r + 1 < nodesPerWave) {
            start_n = lane_bcast_i(off_l, r + 1);
            end_n   = lane_bcast_i(off_l, r + 2);
            cnt_n   = min(end_n - start_n, 64);
            idx_n   = (lane < cnt_n) ? csr[start_n + lane] : 0;
        }
        float agg = bf2f(h[(size_t)node * F + lane]);    // GIN self term (eps=0)
        {
            int k = 0;
            for (; k + 16 <= cnt; k += 16) {
                float vv[16];
#pragma unroll
                for (int u = 0; u < 16; ++u)
                    vv[u] = bf2f(h[(size_t)lane_bcast_i(idx, k + u) * F + lane]);
                float sA = 0.f, sB = 0.f, sC = 0.f, sD = 0.f;
#pragma unroll
                for (int u = 0; u < 4; ++u) {
                    sA += vv[u]; sB += vv[4 + u]; sC += vv[8 + u]; sD += vv[12 + u];
                }
                agg += (sA + sB) + (sC + sD);
            }
            for (; k + 4 <= cnt; k += 4) {
                float v0 = bf2f(h[(size_t)lane_bcast_i(idx, k)     * F + lane]);
                float v1 = bf2f(h[(size_t)lane_bcast_i(idx, k + 1) * F + lane]);
                float v2 = bf2f(h[(size_t)lane_bcast_i(idx, k + 2) * F + lane]);
                float v3 = bf2f(h[(size_t)lane_bcast_i(idx, k + 3) * F + lane]);
                agg += (v0 + v1) + (v2 + v3);
            }
            for (; k < cnt; ++k)
                agg += bf2f(h[(size_t)lane_bcast_i(idx, k) * F + lane]);
        }
        for (int base = start + 64; base < end; base += 64) {
            int c2 = end - base; if (c2 > 64) c2 = 64;
            int idx2 = (lane < c2) ? csr[base + lane] : 0;
            int k = 0;
            for (; k + 4 <= c2; k += 4) {
                float v0 = bf2f(h[(size_t)lane_bcast_i(idx2, k)     * F + lane]);
                float v1 = bf2f(h[(size_t)lane_bcast_i(idx2, k + 1) * F + lane]);
                float v2 = bf2f(h[(size_t)lane_bcast_i(idx2, k + 2) * F + lane]);
                float v3 = bf2f(h[(size_t)lane_bcast_i(idx2, k + 3) * F + lane]);
                agg += (v0 + v1) + (v2 + v3);
            }
            for (; k < c2; ++k)
                agg += bf2f(h[(size_t)lane_bcast_i(idx2, k) * F + lane]);
        }
        float acc = bj;
#pragma unroll
        for (int f = 0; f < F; ++f) acc += lane_bcast(agg, f) * Wl[f * F + lane];
        Y16[(size_t)node * F + lane] = f2bf(acc);
        s1 += acc;
        s2 += acc * acc;
    }
    __shared__ float red[TPB];
    red[t] = s1; __syncthreads();
    if (w == 0) atomicAdd(&stats[lane], red[lane] + red[64 + lane] + red[128 + lane] + red[192 + lane]);
    __syncthreads();
    red[t] = s2; __syncthreads();
    if (w == 0) atomicAdd(&stats[64 + lane], red[lane] + red[64 + lane] + red[128 + lane] + red[192 + lane]);
}

// ---- MFMA layerB: BN(Y16)+ReLU -> @W2+b2 -> ReLU -> Hout(bf16);
//      Yf += Hout @ Wj; optional head BN stats.
// Wave = one 16-row tile (N % 16 == 0 -> no element guards). 16x16x32 bf16
// MFMA; A direct-load (m=lane&15, k=quad*8+j); D->A via wave-private LDS
// (verified m120 pattern); D layout col=lane&15,row=quad*4+reg.
__global__ __launch_bounds__(TPB, 3)
void k_layerB(const u16* __restrict__ Y16, const float* __restrict__ stats,
              const float* __restrict__ g, const float* __restrict__ bt,
              const float* __restrict__ W2, const float* __restrict__ b2,
              const float* __restrict__ Wj,
              u16* __restrict__ Hout, float* __restrict__ Yf,
              float* __restrict__ stats5, int N, int doHead) {
    __shared__ u16 W2l[F * F];
    __shared__ u16 Wjl[F * F];
    __shared__ float scs[F], shs[F];
    __shared__ u16 hbuf[4][16 * F];
    __shared__ float cred1[F], cred2[F];
    int t = threadIdx.x;
    int lane = t & 63, w = t >> 6;
    int m16 = lane & 15, quad = lane >> 4;
    for (int i = t; i < F * F; i += TPB) {
        W2l[i] = f2bf(W2[i]);
        Wjl[i] = f2bf(Wj[i]);
    }
    if (t < F) {
        float mu = stats[t] / (float)N;
        float var = stats[F + t] / (float)N - mu * mu;
        float rs = rsqrtf(var + BN_EPS);
        float sc = rs * g[t];
        scs[t] = sc;
        shs[t] = bt[t] - mu * sc;
    }
    __syncthreads();

    int row0 = (blockIdx.x * 4 + w) * 16;
    float s1v[4] = {0.f, 0.f, 0.f, 0.f}, s2v[4] = {0.f, 0.f, 0.f, 0.f};
    if (row0 < N) {
        // B fragments (bf16): n = nt*16 + m16, k = kc*32 + quad*8 + j
        v8s bf2_[4][2], bfj_[4][2];
#pragma unroll
        for (int nt = 0; nt < 4; ++nt)
#pragma unroll
            for (int kc = 0; kc < 2; ++kc)
#pragma unroll
                for (int j = 0; j < 8; ++j) {
                    int k = kc * 32 + quad * 8 + j;
                    bf2_[nt][kc][j] = (short)W2l[k * F + nt * 16 + m16];
                    bfj_[nt][kc][j] = (short)Wjl[k * F + nt * 16 + m16];
                }
        // A fragments: row = row0 + m16, k = kc*32 + quad*8 + j, BN+ReLU applied
        v8s a1[2];
#pragma unroll
        for (int kc = 0; kc < 2; ++kc) {
            uint4 raw = *(const uint4*)(Y16 + (size_t)(row0 + m16) * F + kc * 32 + quad * 8);
            unsigned uu[4] = {raw.x, raw.y, raw.z, raw.w};
#pragma unroll
            for (int p = 0; p < 4; ++p) {
                int k0 = kc * 32 + quad * 8 + 2 * p;
                float lo = __uint_as_float(uu[p] << 16);
                float hi = __uint_as_float(uu[p] & 0xffff0000u);
                float v0 = fmaxf(lo * scs[k0] + shs[k0], 0.f);
                float v1 = fmaxf(hi * scs[k0 + 1] + shs[k0 + 1], 0.f);
                a1[kc][2 * p]     = (short)f2bf(v0);
                a1[kc][2 * p + 1] = (short)f2bf(v1);
            }
        }
        u16* hb = hbuf[w];
        // GEMM2 + ReLU -> hb (D layout: col = nt*16+m16, row = quad*4+reg)
#pragma unroll
        for (int nt = 0; nt < 4; ++nt) {
            float bb = b2[nt * 16 + m16];
            v4f acc = {bb, bb, bb, bb};
            acc = __builtin_amdgcn_mfma_f32_16x16x32_bf16(a1[0], bf2_[nt][0], acc, 0, 0, 0);
            acc = __builtin_amdgcn_mfma_f32_16x16x32_bf16(a1[1], bf2_[nt][1], acc, 0, 0, 0);
#pragma unroll
            for (int reg = 0; reg < 4; ++reg)
                hb[(quad * 4 + reg) * F + nt * 16 + m16] = f2bf(fmaxf(acc[reg], 0.f));
        }
        // Hout store (wave-private LDS, DS in-order: writes above precede reads)
#pragma unroll
        for (int rr = 0; rr < 4; ++rr) {
            int row = rr * 4 + quad;
            uint2 d = *(const uint2*)(hb + row * F + m16 * 4);
            *(uint2*)(Hout + (size_t)(row0 + row) * F + m16 * 4) = d;
        }
        // JK: A2 from hb in A layout
        v8s a2[2];
#pragma unroll
        for (int kc = 0; kc < 2; ++kc)
            a2[kc] = *(const v8s*)(hb + m16 * F + kc * 32 + quad * 8);
#pragma unroll
        for (int nt = 0; nt < 4; ++nt) {
            v4f acc;
#pragma unroll
            for (int reg = 0; reg < 4; ++reg)
                acc[reg] = Yf[(size_t)(row0 + quad * 4 + reg) * F + nt * 16 + m16];
            acc = __builtin_amdgcn_mfma_f32_16x16x32_bf16(a2[0], bfj_[nt][0], acc, 0, 0, 0);
            acc = __builtin_amdgcn_mfma_f32_16x16x32_bf16(a2[1], bfj_[nt][1], acc, 0, 0, 0);
            float ss1 = 0.f, ss2 = 0.f;
#pragma unroll
            for (int reg = 0; reg < 4; ++reg) {
                float yv = acc[reg];
                Yf[(size_t)(row0 + quad * 4 + reg) * F + nt * 16 + m16] = yv;
                ss1 += yv;
                ss2 += yv * yv;
            }
            s1v[nt] = ss1;
            s2v[nt] = ss2;
        }
    }
    if (doHead) {
        if (t < F) { cred1[t] = 0.f; cred2[t] = 0.f; }
        __syncthreads();
        if (row0 < N) {
#pragma unroll
            for (int nt = 0; nt < 4; ++nt) {
                atomicAdd(&cred1[nt * 16 + m16], s1v[nt]);
                atomicAdd(&cred2[nt * 16 + m16], s2v[nt]);
            }
        }
        __syncthreads();
        if (t < F) {
            atomicAdd(&stats5[t], cred1[t]);
            atomicAdd(&stats5[F + t], cred2[t]);
        }
    }
}

// ---- head: BN(Yf)+ReLU -> @mlpW2+b2 -> pooled add into out[graph] -------
__global__ __launch_bounds__(TPB, 4)
void k_final(const float* __restrict__ Yf, const float* __restrict__ stats,
             const float* __restrict__ g, const float* __restrict__ bt,
             const float* __restrict__ W2, const float* __restrict__ b2,
             const int* __restrict__ batch, float* __restrict__ out,
             int N, int rowsPerWave) {
    int t = threadIdx.x;
    int lane = t & 63, w = t >> 6;
    float wcol[F];
#pragma unroll
    for (int f = 0; f < F; ++f) wcol[f] = W2[f * F + lane];
    float mu = stats[lane] / (float)N;
    float var = stats[64 + lane] / (float)N - mu * mu;
    float rs = rsqrtf(var + BN_EPS);
    float sc = rs * g[lane];
    float sh = bt[lane] - mu * sc;
    float bj = b2[lane];
    int row0 = (blockIdx.x * 4 + w) * rowsPerWave;
    int curg = -1;
    float accg = 0.f;
    for (int r = 0; r < rowsPerWave; ++r) {
        int row = row0 + r;
        if (row >= N) break;
        float v = fmaxf(Yf[(size_t)row * F + lane] * sc + sh, 0.f);
        float acc = bj;
#pragma unroll
        for (int f = 0; f < F; ++f) acc += lane_bcast(v, f) * wcol[f];
        int gid = batch[row];
        if (gid != curg) {
            if (curg >= 0) atomicAdd(&out[(size_t)curg * F + lane], accg);
            curg = gid;
            accg = 0.f;
        }
        accg += acc;
    }
    if (curg >= 0) atomicAdd(&out[(size_t)curg * F + lane], accg);
}

// ---- launcher -----------------------------------------------------------

extern "C" void kernel_launch(void* const* d_in, const int* in_sizes, int n_in,
                              void* d_out, int out_size, void* d_ws, size_t ws_size,
                              hipStream_t stream) {
    const float* x      = (const float*)d_in[0];
    const int*   ei     = (const int*)d_in[1];
    const int*   batch  = (const int*)d_in[2];
    const float* convW1 = (const float*)d_in[3];
    const float* convb1 = (const float*)d_in[4];
    const float* convg  = (const float*)d_in[5];
    const float* convbt = (const float*)d_in[6];
    const float* convW2 = (const float*)d_in[7];
    const float* convb2 = (const float*)d_in[8];
    const float* mlpW1  = (const float*)d_in[9];
    const float* mlpb1  = (const float*)d_in[10];
    const float* mlpg   = (const float*)d_in[11];
    const float* mlpbt  = (const float*)d_in[12];
    const float* mlpW2  = (const float*)d_in[13];
    const float* mlpb2  = (const float*)d_in[14];

    const int N = in_sizes[0] / F;             // 50000
    const int E = in_sizes[1] / 2;             // 800000
    const int L = in_sizes[3] / (F * F);       // 5

    const int* src = ei;
    const int* dst = ei + E;

    char* w = (char*)d_ws;
    size_t off = 0;
    auto alloc = [&](size_t bytes) {
        void* p = w + off;
        off = (off + bytes + 255) & ~(size_t)255;
        return p;
    };
    u16*   x16     = (u16*)alloc((size_t)N * F * 2);
    u16*   hA16    = (u16*)alloc((size_t)N * F * 2);
    u16*   hB16    = (u16*)alloc((size_t)N * F * 2);
    u16*   Ytmp16  = (u16*)alloc((size_t)N * F * 2);
    float* Yf      = (float*)alloc((size_t)N * F * 4);
    int*   deg     = (int*)alloc((size_t)N * 4);
    int*   offs    = (int*)alloc((size_t)(N + 1) * 4);
    int*   cursor  = (int*)alloc((size_t)N * 4);
    int*   csr_src = (int*)alloc((size_t)E * 4);
    int*   part    = (int*)alloc((size_t)SCAN_B * 4);
    float* stats   = (float*)alloc((size_t)(L + 1) * 128 * 4);

    hipMemsetAsync(deg, 0, (size_t)N * 4, stream);
    hipMemsetAsync(stats, 0, (size_t)(L + 1) * 128 * 4, stream);
    hipMemsetAsync(d_out, 0, (size_t)out_size * 4, stream);

    const int edgeBlocks = (E + TPB - 1) / TPB;

    k_hist<<<edgeBlocks, TPB, 0, stream>>>(dst, deg, E);
    k_scan_part<<<SCAN_B, TPB, 0, stream>>>(deg, part, N);
    k_scan_apply<<<SCAN_B, TPB, 0, stream>>>(deg, part, offs, cursor, N);
    k_fill<<<edgeBlocks, TPB, 0, stream>>>(src, dst, cursor, csr_src, E);

    const int NPW_A = 8;     // R12/R15 proven config; 1563 blocks
    const int RPW   = 8;
    const int RPW_F = 16;
    const int blocksA = (N + 4 * NPW_A - 1) / (4 * NPW_A);
    const int blocksD = (N + 4 * RPW - 1) / (4 * RPW);
    const int blocksB = (N + 63) / 64;         // MFMA layerB: 16 rows/wave
    const int blocksF = (N + 4 * RPW_F - 1) / (4 * RPW_F);

    // fused bf16-convert + JK-init (reads x once)
    k_prep<<<blocksD, TPB, 0, stream>>>(x, x16, mlpW1, mlpb1, Yf, N, RPW);

    const u16* h_cur = x16;
    for (int l = 0; l < L; ++l) {
        u16* h_next = (l & 1) ? hB16 : hA16;
        k_gather_gemm<<<blocksA, TPB, 0, stream>>>(h_cur, offs, csr_src,
                                                   convW1 + l * F * F, convb1 + l * F,
                                                   Ytmp16, stats + l * 128, N, NPW_A);
        k_layerB<<<blocksB, TPB, 0, stream>>>(Ytmp16, stats + l * 128,
                                              convg + l * F, convbt + l * F,
                                              convW2 + l * F * F, convb2 + l * F,
                                              mlpW1 + (l + 1) * F * F,
                                              h_next, Yf, stats + L * 128,
                                              N, l == L - 1);
        h_cur = h_next;
    }

    k_final<<<blocksF, TPB, 0, stream>>>(Yf, stats + L * 128, mlpg, mlpbt,
                                         mlpW2, mlpb2, batch, (float*)d_out, N, RPW_F);
}

// Round 20
// 613.825 us; speedup vs baseline: 2.5215x; 1.0278x over previous
//
#include <hip/hip_runtime.h>

#define F 64
#define TPB 256
#define SCAN_B 64
#define BN_EPS 1e-5f

typedef unsigned short u16;
typedef __attribute__((ext_vector_type(8))) short v8s;
typedef __attribute__((ext_vector_type(4))) float v4f;

__device__ __forceinline__ float lane_bcast(float v, int l) {
    return __int_as_float(__builtin_amdgcn_readlane(__float_as_int(v), l));
}
__device__ __forceinline__ int lane_bcast_i(int v, int l) {
    return __builtin_amdgcn_readlane(v, l);
}
__device__ __forceinline__ float bf2f(u16 u) {
    return __uint_as_float(((unsigned int)u) << 16);
}
__device__ __forceinline__ u16 f2bf(float f) {
    unsigned int u = __float_as_uint(f);
    unsigned int r = (u + 0x7fffu + ((u >> 16) & 1u)) >> 16;   // RNE
    return (u16)r;
}

// ---- CSR build ----------------------------------------------------------

__global__ __launch_bounds__(TPB) void k_hist(const int* __restrict__ dst,
                                              int* __restrict__ deg, int E) {
    int e = blockIdx.x * blockDim.x + threadIdx.x;
    if (e < E) atomicAdd(&deg[dst[e]], 1);
}

__global__ __launch_bounds__(TPB) void k_scan_part(const int* __restrict__ deg,
                                                   int* __restrict__ part, int N) {
    __shared__ int red[TPB];
    int chunk = (N + SCAN_B - 1) / SCAN_B;
    int lo = blockIdx.x * chunk, hi = min(lo + chunk, N);
    int t = threadIdx.x;
    int s = 0;
    for (int i = lo + t; i < hi; i += TPB) s += deg[i];
    red[t] = s; __syncthreads();
    for (int d = TPB / 2; d > 0; d >>= 1) {
        if (t < d) red[t] += red[t + d];
        __syncthreads();
    }
    if (t == 0) part[blockIdx.x] = red[0];
}

__global__ __launch_bounds__(TPB) void k_scan_apply(const int* __restrict__ deg,
                                                    const int* __restrict__ part,
                                                    int* __restrict__ offs,
                                                    int* __restrict__ cursor, int N) {
    __shared__ int ts[TPB];
    __shared__ int pb_s;
    int t = threadIdx.x;
    ts[t] = (t < blockIdx.x) ? part[t] : 0;
    __syncthreads();
    for (int d = TPB / 2; d > 0; d >>= 1) {
        if (t < d) ts[t] += ts[t + d];
        __syncthreads();
    }
    if (t == 0) pb_s = ts[0];
    __syncthreads();
    int pbase = pb_s;
    __syncthreads();
    int chunk = (N + SCAN_B - 1) / SCAN_B;
    int sub = (chunk + TPB - 1) / TPB;
    int lo = blockIdx.x * chunk;
    int blockhi = min(lo + chunk, N);
    int mylo = min(lo + t * sub, blockhi);
    int myhi = min(mylo + sub, blockhi);
    int s = 0;
    for (int i = mylo; i < myhi; ++i) s += deg[i];
    ts[t] = s; __syncthreads();
    for (int d = 1; d < TPB; d <<= 1) {
        int a = (t >= d) ? ts[t - d] : 0;
        __syncthreads();
        ts[t] += a;
        __syncthreads();
    }
    int run = pbase + ts[t] - s;
    for (int i = mylo; i < myhi; ++i) {
        offs[i] = run; cursor[i] = run; run += deg[i];
    }
    if (blockIdx.x == SCAN_B - 1 && t == TPB - 1) offs[N] = pbase + ts[TPB - 1];
}

__global__ __launch_bounds__(TPB) void k_fill(const int* __restrict__ src,
                                              const int* __restrict__ dst,
                                              int* __restrict__ cursor,
                                              int* __restrict__ csr_src, int E) {
    int e = blockIdx.x * blockDim.x + threadIdx.x;
    if (e >= E) return;
    int pos = atomicAdd(&cursor[dst[e]], 1);
    csr_src[pos] = src[e];
}

// ---- MFMA prep: x16 = bf16(x); Yf = x @ Wj + bias -----------------------
// Wave = 16 rows. A-fragment load covers each (row,k) exactly once ->
// x16 conversion falls out for free. D layout: col=nt*16+m16, row=quad*4+reg.
__global__ __launch_bounds__(TPB, 4)
void k_prep(const float* __restrict__ x, u16* __restrict__ x16,
            const float* __restrict__ Wj, const float* __restrict__ bias,
            float* __restrict__ Yf, int N) {
    __shared__ u16 Wjl[F * F];
    int t = threadIdx.x;
    int lane = t & 63, w = t >> 6;
    int m16 = lane & 15, quad = lane >> 4;
    for (int i = t; i < F * F; i += TPB) Wjl[i] = f2bf(Wj[i]);
    __syncthreads();
    int row0 = (blockIdx.x * 4 + w) * 16;
    if (row0 >= N) return;
    v8s bfj[4][2];
#pragma unroll
    for (int nt = 0; nt < 4; ++nt)
#pragma unroll
        for (int kc = 0; kc < 2; ++kc)
#pragma unroll
            for (int j = 0; j < 8; ++j)
                bfj[nt][kc][j] = (short)Wjl[(kc * 32 + quad * 8 + j) * F + nt * 16 + m16];
    v8s a[2];
#pragma unroll
    for (int kc = 0; kc < 2; ++kc) {
        const float* xp = x + (size_t)(row0 + m16) * F + kc * 32 + quad * 8;
        float4 r0 = *(const float4*)xp;
        float4 r1 = *(const float4*)(xp + 4);
        u16 b[8] = {f2bf(r0.x), f2bf(r0.y), f2bf(r0.z), f2bf(r0.w),
                    f2bf(r1.x), f2bf(r1.y), f2bf(r1.z), f2bf(r1.w)};
#pragma unroll
        for (int j = 0; j < 8; ++j) a[kc][j] = (short)b[j];
        *(uint4*)(x16 + (size_t)(row0 + m16) * F + kc * 32 + quad * 8) = *(const uint4*)b;
    }
#pragma unroll
    for (int nt = 0; nt < 4; ++nt) {
        float bb = bias[nt * 16 + m16];
        v4f acc = {bb, bb, bb, bb};
        acc = __builtin_amdgcn_mfma_f32_16x16x32_bf16(a[0], bfj[nt][0], acc, 0, 0, 0);
        acc = __builtin_amdgcn_mfma_f32_16x16x32_bf16(a[1], bfj[nt][1], acc, 0, 0, 0);
#pragma unroll
        for (int reg = 0; reg < 4; ++reg)
            Yf[(size_t)(row0 + quad * 4 + reg) * F + nt * 16 + m16] = acc[reg];
    }
}

// ---- fused gather + GEMM1 + BN stats (R15 structure; Y stored bf16) -----
__global__ __launch_bounds__(TPB, 8)
void k_gather_gemm(const u16* __restrict__ h, const int* __restrict__ offs,
                   const int* __restrict__ csr,
                   const float* __restrict__ W, const float* __restrict__ bias,
                   u16* __restrict__ Y16, float* __restrict__ stats,
                   int N, int nodesPerWave) {
    __shared__ float Wl[F * F];
    int t = threadIdx.x;
    int lane = t & 63, w = t >> 6;
    for (int i = t; i < F * F; i += TPB) Wl[i] = W[i];
    __syncthreads();
    float bj = bias[lane];
    int node0 = (blockIdx.x * 4 + w) * nodesPerWave;
    int off_l = 0;
    if (lane <= nodesPerWave) off_l = offs[min(node0 + lane, N)];
    float s1 = 0.f, s2 = 0.f;
    int start_n = lane_bcast_i(off_l, 0);
    int end_n   = lane_bcast_i(off_l, 1);
    int cnt_n   = min(end_n - start_n, 64);
    int idx_n   = (lane < cnt_n) ? csr[start_n + lane] : 0;
    for (int r = 0; r < nodesPerWave; ++r) {
        int node = node0 + r;
        if (node >= N) break;
        int start = start_n, end = end_n, cnt = cnt_n, idx = idx_n;
        if (r + 1 < nodesPerWave) {
            start_n = lane_bcast_i(off_l, r + 1);
            end_n   = lane_bcast_i(off_l, r + 2);
            cnt_n   = min(end_n - start_n, 64);
            idx_n   = (lane < cnt_n) ? csr[start_n + lane] : 0;
        }
        float agg = bf2f(h[(size_t)node * F + lane]);    // GIN self term (eps=0)
        {
            int k = 0;
            for (; k + 16 <= cnt; k += 16) {
                float vv[16];
#pragma unroll
                for (int u = 0; u < 16; ++u)
                    vv[u] = bf2f(h[(size_t)lane_bcast_i(idx, k + u) * F + lane]);
                float sA = 0.f, sB = 0.f, sC = 0.f, sD = 0.f;
#pragma unroll
                for (int u = 0; u < 4; ++u) {
                    sA += vv[u]; sB += vv[4 + u]; sC += vv[8 + u]; sD += vv[12 + u];
                }
                agg += (sA + sB) + (sC + sD);
            }
            for (; k + 4 <= cnt; k += 4) {
                float v0 = bf2f(h[(size_t)lane_bcast_i(idx, k)     * F + lane]);
                float v1 = bf2f(h[(size_t)lane_bcast_i(idx, k + 1) * F + lane]);
                float v2 = bf2f(h[(size_t)lane_bcast_i(idx, k + 2) * F + lane]);
                float v3 = bf2f(h[(size_t)lane_bcast_i(idx, k + 3) * F + lane]);
                agg += (v0 + v1) + (v2 + v3);
            }
            for (; k < cnt; ++k)
                agg += bf2f(h[(size_t)lane_bcast_i(idx, k) * F + lane]);
        }
        for (int base = start + 64; base < end; base += 64) {
            int c2 = end - base; if (c2 > 64) c2 = 64;
            int idx2 = (lane < c2) ? csr[base + lane] : 0;
            int k = 0;
            for (; k + 4 <= c2; k += 4) {
                float v0 = bf2f(h[(size_t)lane_bcast_i(idx2, k)     * F + lane]);
                float v1 = bf2f(h[(size_t)lane_bcast_i(idx2, k + 1) * F + lane]);
                float v2 = bf2f(h[(size_t)lane_bcast_i(idx2, k + 2) * F + lane]);
                float v3 = bf2f(h[(size_t)lane_bcast_i(idx2, k + 3) * F + lane]);
                agg += (v0 + v1) + (v2 + v3);
            }
            for (; k < c2; ++k)
                agg += bf2f(h[(size_t)lane_bcast_i(idx2, k) * F + lane]);
        }
        float acc = bj;
#pragma unroll
        for (int f = 0; f < F; ++f) acc += lane_bcast(agg, f) * Wl[f * F + lane];
        Y16[(size_t)node * F + lane] = f2bf(acc);
        s1 += acc;
        s2 += acc * acc;
    }
    __shared__ float red[TPB];
    red[t] = s1; __syncthreads();
    if (w == 0) atomicAdd(&stats[lane], red[lane] + red[64 + lane] + red[128 + lane] + red[192 + lane]);
    __syncthreads();
    red[t] = s2; __syncthreads();
    if (w == 0) atomicAdd(&stats[64 + lane], red[lane] + red[64 + lane] + red[128 + lane] + red[192 + lane]);
}

// ---- MFMA layerB (R19-verified) -----------------------------------------
__global__ __launch_bounds__(TPB, 3)
void k_layerB(const u16* __restrict__ Y16, const float* __restrict__ stats,
              const float* __restrict__ g, const float* __restrict__ bt,
              const float* __restrict__ W2, const float* __restrict__ b2,
              const float* __restrict__ Wj,
              u16* __restrict__ Hout, float* __restrict__ Yf,
              float* __restrict__ stats5, int N, int doHead) {
    __shared__ u16 W2l[F * F];
    __shared__ u16 Wjl[F * F];
    __shared__ float scs[F], shs[F];
    __shared__ u16 hbuf[4][16 * F];
    __shared__ float cred1[F], cred2[F];
    int t = threadIdx.x;
    int lane = t & 63, w = t >> 6;
    int m16 = lane & 15, quad = lane >> 4;
    for (int i = t; i < F * F; i += TPB) {
        W2l[i] = f2bf(W2[i]);
        Wjl[i] = f2bf(Wj[i]);
    }
    if (t < F) {
        float mu = stats[t] / (float)N;
        float var = stats[F + t] / (float)N - mu * mu;
        float rs = rsqrtf(var + BN_EPS);
        float sc = rs * g[t];
        scs[t] = sc;
        shs[t] = bt[t] - mu * sc;
    }
    __syncthreads();

    int row0 = (blockIdx.x * 4 + w) * 16;
    float s1v[4] = {0.f, 0.f, 0.f, 0.f}, s2v[4] = {0.f, 0.f, 0.f, 0.f};
    if (row0 < N) {
        v8s bf2_[4][2], bfj_[4][2];
#pragma unroll
        for (int nt = 0; nt < 4; ++nt)
#pragma unroll
            for (int kc = 0; kc < 2; ++kc)
#pragma unroll
                for (int j = 0; j < 8; ++j) {
                    int k = kc * 32 + quad * 8 + j;
                    bf2_[nt][kc][j] = (short)W2l[k * F + nt * 16 + m16];
                    bfj_[nt][kc][j] = (short)Wjl[k * F + nt * 16 + m16];
                }
        v8s a1[2];
#pragma unroll
        for (int kc = 0; kc < 2; ++kc) {
            uint4 raw = *(const uint4*)(Y16 + (size_t)(row0 + m16) * F + kc * 32 + quad * 8);
            unsigned uu[4] = {raw.x, raw.y, raw.z, raw.w};
#pragma unroll
            for (int p = 0; p < 4; ++p) {
                int k0 = kc * 32 + quad * 8 + 2 * p;
                float lo = __uint_as_float(uu[p] << 16);
                float hi = __uint_as_float(uu[p] & 0xffff0000u);
                float v0 = fmaxf(lo * scs[k0] + shs[k0], 0.f);
                float v1 = fmaxf(hi * scs[k0 + 1] + shs[k0 + 1], 0.f);
                a1[kc][2 * p]     = (short)f2bf(v0);
                a1[kc][2 * p + 1] = (short)f2bf(v1);
            }
        }
        u16* hb = hbuf[w];
#pragma unroll
        for (int nt = 0; nt < 4; ++nt) {
            float bb = b2[nt * 16 + m16];
            v4f acc = {bb, bb, bb, bb};
            acc = __builtin_amdgcn_mfma_f32_16x16x32_bf16(a1[0], bf2_[nt][0], acc, 0, 0, 0);
            acc = __builtin_amdgcn_mfma_f32_16x16x32_bf16(a1[1], bf2_[nt][1], acc, 0, 0, 0);
#pragma unroll
            for (int reg = 0; reg < 4; ++reg)
                hb[(quad * 4 + reg) * F + nt * 16 + m16] = f2bf(fmaxf(acc[reg], 0.f));
        }
#pragma unroll
        for (int rr = 0; rr < 4; ++rr) {
            int row = rr * 4 + quad;
            uint2 d = *(const uint2*)(hb + row * F + m16 * 4);
            *(uint2*)(Hout + (size_t)(row0 + row) * F + m16 * 4) = d;
        }
        v8s a2[2];
#pragma unroll
        for (int kc = 0; kc < 2; ++kc)
            a2[kc] = *(const v8s*)(hb + m16 * F + kc * 32 + quad * 8);
#pragma unroll
        for (int nt = 0; nt < 4; ++nt) {
            v4f acc;
#pragma unroll
            for (int reg = 0; reg < 4; ++reg)
                acc[reg] = Yf[(size_t)(row0 + quad * 4 + reg) * F + nt * 16 + m16];
            acc = __builtin_amdgcn_mfma_f32_16x16x32_bf16(a2[0], bfj_[nt][0], acc, 0, 0, 0);
            acc = __builtin_amdgcn_mfma_f32_16x16x32_bf16(a2[1], bfj_[nt][1], acc, 0, 0, 0);
            float ss1 = 0.f, ss2 = 0.f;
#pragma unroll
            for (int reg = 0; reg < 4; ++reg) {
                float yv = acc[reg];
                Yf[(size_t)(row0 + quad * 4 + reg) * F + nt * 16 + m16] = yv;
                ss1 += yv;
                ss2 += yv * yv;
            }
            s1v[nt] = ss1;
            s2v[nt] = ss2;
        }
    }
    if (doHead) {
        if (t < F) { cred1[t] = 0.f; cred2[t] = 0.f; }
        __syncthreads();
        if (row0 < N) {
#pragma unroll
            for (int nt = 0; nt < 4; ++nt) {
                atomicAdd(&cred1[nt * 16 + m16], s1v[nt]);
                atomicAdd(&cred2[nt * 16 + m16], s2v[nt]);
            }
        }
        __syncthreads();
        if (t < F) {
            atomicAdd(&stats5[t], cred1[t]);
            atomicAdd(&stats5[F + t], cred2[t]);
        }
    }
}

// ---- MFMA head: BN(Yf)+ReLU -> @mlpW2+b2 -> pooled add into out[graph] --
// Run-length pooling over the 4 consecutive D-rows each lane owns.
__global__ __launch_bounds__(TPB, 4)
void k_final(const float* __restrict__ Yf, const float* __restrict__ stats,
             const float* __restrict__ g, const float* __restrict__ bt,
             const float* __restrict__ W2, const float* __restrict__ b2,
             const int* __restrict__ batch, float* __restrict__ out, int N) {
    __shared__ u16 W2l[F * F];
    __shared__ float scs[F], shs[F];
    int t = threadIdx.x;
    int lane = t & 63, w = t >> 6;
    int m16 = lane & 15, quad = lane >> 4;
    for (int i = t; i < F * F; i += TPB) W2l[i] = f2bf(W2[i]);
    if (t < F) {
        float mu = stats[t] / (float)N;
        float var = stats[F + t] / (float)N - mu * mu;
        float rs = rsqrtf(var + BN_EPS);
        float sc = rs * g[t];
        scs[t] = sc;
        shs[t] = bt[t] - mu * sc;
    }
    __syncthreads();
    int row0 = (blockIdx.x * 4 + w) * 16;
    if (row0 >= N) return;
    v8s bw[4][2];
#pragma unroll
    for (int nt = 0; nt < 4; ++nt)
#pragma unroll
        for (int kc = 0; kc < 2; ++kc)
#pragma unroll
            for (int j = 0; j < 8; ++j)
                bw[nt][kc][j] = (short)W2l[(kc * 32 + quad * 8 + j) * F + nt * 16 + m16];
    v8s a[2];
#pragma unroll
    for (int kc = 0; kc < 2; ++kc) {
        const float* yp = Yf + (size_t)(row0 + m16) * F + kc * 32 + quad * 8;
        float4 r0 = *(const float4*)yp;
        float4 r1 = *(const float4*)(yp + 4);
        float vals[8] = {r0.x, r0.y, r0.z, r0.w, r1.x, r1.y, r1.z, r1.w};
#pragma unroll
        for (int j = 0; j < 8; ++j) {
            int k = kc * 32 + quad * 8 + j;
            a[kc][j] = (short)f2bf(fmaxf(vals[j] * scs[k] + shs[k], 0.f));
        }
    }
    v4f accv[4];
#pragma unroll
    for (int nt = 0; nt < 4; ++nt) {
        float bb = b2[nt * 16 + m16];
        v4f acc = {bb, bb, bb, bb};
        acc = __builtin_amdgcn_mfma_f32_16x16x32_bf16(a[0], bw[nt][0], acc, 0, 0, 0);
        acc = __builtin_amdgcn_mfma_f32_16x16x32_bf16(a[1], bw[nt][1], acc, 0, 0, 0);
        accv[nt] = acc;
    }
    int gid_prev = -1;
    float psum[4] = {0.f, 0.f, 0.f, 0.f};
#pragma unroll
    for (int reg = 0; reg < 4; ++reg) {
        int gid = batch[row0 + quad * 4 + reg];
        if (gid != gid_prev) {
            if (gid_prev >= 0)
#pragma unroll
                for (int nt = 0; nt < 4; ++nt)
                    atomicAdd(&out[(size_t)gid_prev * F + nt * 16 + m16], psum[nt]);
            gid_prev = gid;
            psum[0] = psum[1] = psum[2] = psum[3] = 0.f;
        }
#pragma unroll
        for (int nt = 0; nt < 4; ++nt) psum[nt] += accv[nt][reg];
    }
    if (gid_prev >= 0)
#pragma unroll
        for (int nt = 0; nt < 4; ++nt)
            atomicAdd(&out[(size_t)gid_prev * F + nt * 16 + m16], psum[nt]);
}

// ---- launcher -----------------------------------------------------------

extern "C" void kernel_launch(void* const* d_in, const int* in_sizes, int n_in,
                              void* d_out, int out_size, void* d_ws, size_t ws_size,
                              hipStream_t stream) {
    const float* x      = (const float*)d_in[0];
    const int*   ei     = (const int*)d_in[1];
    const int*   batch  = (const int*)d_in[2];
    const float* convW1 = (const float*)d_in[3];
    const float* convb1 = (const float*)d_in[4];
    const float* convg  = (const float*)d_in[5];
    const float* convbt = (const float*)d_in[6];
    const float* convW2 = (const float*)d_in[7];
    const float* convb2 = (const float*)d_in[8];
    const float* mlpW1  = (const float*)d_in[9];
    const float* mlpb1  = (const float*)d_in[10];
    const float* mlpg   = (const float*)d_in[11];
    const float* mlpbt  = (const float*)d_in[12];
    const float* mlpW2  = (const float*)d_in[13];
    const float* mlpb2  = (const float*)d_in[14];

    const int N = in_sizes[0] / F;             // 50000
    const int E = in_sizes[1] / 2;             // 800000
    const int L = in_sizes[3] / (F * F);       // 5

    const int* src = ei;
    const int* dst = ei + E;

    char* w = (char*)d_ws;
    size_t off = 0;
    auto alloc = [&](size_t bytes) {
        void* p = w + off;
        off = (off + bytes + 255) & ~(size_t)255;
        return p;
    };
    u16*   x16     = (u16*)alloc((size_t)N * F * 2);
    u16*   hA16    = (u16*)alloc((size_t)N * F * 2);
    u16*   hB16    = (u16*)alloc((size_t)N * F * 2);
    u16*   Ytmp16  = (u16*)alloc((size_t)N * F * 2);
    float* Yf      = (float*)alloc((size_t)N * F * 4);
    int*   deg     = (int*)alloc((size_t)N * 4);
    int*   offs    = (int*)alloc((size_t)(N + 1) * 4);
    int*   cursor  = (int*)alloc((size_t)N * 4);
    int*   csr_src = (int*)alloc((size_t)E * 4);
    int*   part    = (int*)alloc((size_t)SCAN_B * 4);
    float* stats   = (float*)alloc((size_t)(L + 1) * 128 * 4);

    hipMemsetAsync(deg, 0, (size_t)N * 4, stream);
    hipMemsetAsync(stats, 0, (size_t)(L + 1) * 128 * 4, stream);
    hipMemsetAsync(d_out, 0, (size_t)out_size * 4, stream);

    const int edgeBlocks = (E + TPB - 1) / TPB;

    k_hist<<<edgeBlocks, TPB, 0, stream>>>(dst, deg, E);
    k_scan_part<<<SCAN_B, TPB, 0, stream>>>(deg, part, N);
    k_scan_apply<<<SCAN_B, TPB, 0, stream>>>(deg, part, offs, cursor, N);
    k_fill<<<edgeBlocks, TPB, 0, stream>>>(src, dst, cursor, csr_src, E);

    const int NPW_A = 8;     // R12/R15 proven config; 1563 blocks
    const int blocksA = (N + 4 * NPW_A - 1) / (4 * NPW_A);
    const int blocksB = (N + 63) / 64;         // MFMA tiles: 16 rows/wave

    k_prep<<<blocksB, TPB, 0, stream>>>(x, x16, mlpW1, mlpb1, Yf, N);

    const u16* h_cur = x16;
    for (int l = 0; l < L; ++l) {
        u16* h_next = (l & 1) ? hB16 : hA16;
        k_gather_gemm<<<blocksA, TPB, 0, stream>>>(h_cur, offs, csr_src,
                                                   convW1 + l * F * F, convb1 + l * F,
                                                   Ytmp16, stats + l * 128, N, NPW_A);
        k_layerB<<<blocksB, TPB, 0, stream>>>(Ytmp16, stats + l * 128,
                                              convg + l * F, convbt + l * F,
                                              convW2 + l * F * F, convb2 + l * F,
                                              mlpW1 + (l + 1) * F * F,
                                              h_next, Yf, stats + L * 128,
                                              N, l == L - 1);
        h_cur = h_next;
    }

    k_final<<<blocksB, TPB, 0, stream>>>(Yf, stats + L * 128, mlpg, mlpbt,
                                         mlpW2, mlpb2, batch, (float*)d_out, N);
}